// Round 6
// baseline (1271.645 us; speedup 1.0000x reference)
//
#include <hip/hip_runtime.h>

typedef unsigned short u16;
typedef __bf16 bf16x8 __attribute__((ext_vector_type(8)));
typedef float f32x4 __attribute__((ext_vector_type(4)));
typedef float f32x4v __attribute__((ext_vector_type(4)));
typedef unsigned int u32x2 __attribute__((ext_vector_type(2)));

#define NSENT 40
#define SLEN 30
#define QLEN 20
#define ALEN 12
#define SCTX 2560
#define SLOT 24              // u16 (or fp32) values per lane-slot
#define TP 12288             // 512*24 elements per (block,t) plane

__device__ __forceinline__ float b2f(u16 u){ union{float f; unsigned i;} v; v.i = ((unsigned)u)<<16; return v.f; }
__device__ __forceinline__ u16 f2b(float f){ union{float f; unsigned u;} v; v.f=f; unsigned u=v.u; u += ((u>>16)&1u) + 0x7fffu; return (u16)(u>>16); }
__device__ __forceinline__ float sigm(float x){ return __builtin_amdgcn_rcpf(1.f + __expf(-x)); }
__device__ __forceinline__ float tanh_(float x){
  float a = fminf(fmaxf(2.f*x, -30.f), 30.f);
  float e = __expf(a);
  return 1.f - 2.f*__builtin_amdgcn_rcpf(e + 1.f);
}
__device__ __forceinline__ f32x4 mfma16(bf16x8 a, bf16x8 b, f32x4 c){
  return __builtin_amdgcn_mfma_f32_16x16x32_bf16(a, b, c, 0, 0, 0);
}

// ---------------------------------------------------------------------------
// Prep: pi-permute (n' = g16*48 + gate*16 + c <-> j = gate*256 + g16*16 + c)
// 10 weight mats -> bf16 P0..P9; gW1 plain bf16; 10 pi-permuted fp32 biases.
// ---------------------------------------------------------------------------
__global__ void k_prep(
    const float* cWih, const float* cWhh, const float* qWih, const float* qWhh,
    const float* aWih, const float* aWhh, const float* tWih, const float* tWhh,
    const float* mWih, const float* mWhh, const float* gW1,
    const float* cbih, const float* cbhh, const float* qbih, const float* qbhh,
    const float* abih, const float* abhh, const float* tbih, const float* tbhh,
    const float* mbih, const float* mbhh,
    u16* P0,u16* P1,u16* P2,u16* P3,u16* P4,u16* P5,u16* P6,u16* P7,u16* P8,u16* P9,
    u16* PgW1,
    float* B0,float* B1,float* B2,float* B3,float* B4,float* B5,float* B6,float* B7,
    float* B8,float* B9)
{
  int i = blockIdx.x*512 + threadIdx.x;   // 4751*512 = 2,432,512
  if (i < 1966080){
    int seg = i/196608; int e = i - seg*196608;
    int np = e>>8, k = e&255;
    int g16 = np/48, rem = np - g16*48, gate = rem>>4, cc = rem&15;
    int j = gate*256 + g16*16 + cc;
    const float* S; u16* D;
    switch(seg){
      case 0: S=cWih; D=P0; break; case 1: S=cWhh; D=P1; break;
      case 2: S=qWih; D=P2; break; case 3: S=qWhh; D=P3; break;
      case 4: S=aWih; D=P4; break; case 5: S=aWhh; D=P5; break;
      case 6: S=tWih; D=P6; break; case 7: S=tWhh; D=P7; break;
      case 8: S=mWih; D=P8; break; default: S=mWhh; D=P9; break;
    }
    D[e] = f2b(S[j*256 + k]);
  } else if (i < 2424832){
    int e = i - 1966080;
    PgW1[e] = f2b(gW1[e]);
  } else {
    int e = i - 2424832;                  // 7680 = 10*768
    int seg = e/768; int np = e - seg*768;
    int g16 = np/48, rem = np - g16*48, gate = rem>>4, cc = rem&15;
    int j = gate*256 + g16*16 + cc;
    const float* S; float* D;
    switch(seg){
      case 0: S=cbih; D=B0; break; case 1: S=cbhh; D=B1; break;
      case 2: S=qbih; D=B2; break; case 3: S=qbhh; D=B3; break;
      case 4: S=abih; D=B4; break; case 5: S=abhh; D=B5; break;
      case 6: S=tbih; D=B6; break; case 7: S=tbhh; D=B7; break;
      case 8: S=mbih; D=B8; break; default: S=mbhh; D=B9; break;
    }
    D[np] = S[j];
  }
}

// ---------------------------------------------------------------------------
// x-projections. 64 rows/block (32 seqs x 2 t); nt embed loads + nt gi stores
// keep the 393KB weight matrix L2-resident.
// gi plane layout: plane*TP + jj*6144 + (w8*64+lane)*12 + (r*3+g).
// ---------------------------------------------------------------------------
__global__ __launch_bounds__(512, 4) void k_xproj(
    const int* c_p, const int* q_p, const int* a1p, const int* a2p,
    const float* embed,
    const u16* cWihP, const u16* qWihP, const u16* aWihP,
    const float* cBih, const float* qBih, const float* aBih,
    u16* gi_c, u16* gi_q, u16* gi_a1, u16* gi_a2)
{
  __shared__ u16 xb[64][288];
  int bid=blockIdx.x, tid=threadIdx.x;
  const int* toks; const u16* W; const float* bias; u16* out; int T, blk32, t0;
  if (bid < 1200){ toks=c_p; W=cWihP; bias=cBih; out=gi_c; T=SLEN; blk32=bid/15; t0=(bid-blk32*15)*2; }
  else if (bid < 1220){ int e=bid-1200; toks=q_p; W=qWihP; bias=qBih; out=gi_q; T=QLEN; blk32=e/10; t0=(e-blk32*10)*2; }
  else if (bid < 1232){ int e=bid-1220; toks=a1p; W=aWihP; bias=aBih; out=gi_a1; T=ALEN; blk32=e/6; t0=(e-blk32*6)*2; }
  else               { int e=bid-1232; toks=a2p; W=aWihP; bias=aBih; out=gi_a2; T=ALEN; blk32=e/6; t0=(e-blk32*6)*2; }
  int seq0 = blk32*32;
  #pragma unroll
  for (int p=0;p<8;p++){
    int i=p*512+tid; int row=i>>6, f4=i&63;   // row wave-uniform
    int tp=row>>5, sm=row&31;
    int tok = toks[(seq0+sm)*T + t0+tp];
    f32x4v v = __builtin_nontemporal_load((const f32x4v*)(embed + (long)tok*256) + f4);
    unsigned lo = (unsigned)f2b(v[0]) | ((unsigned)f2b(v[1])<<16);
    unsigned hi = (unsigned)f2b(v[2]) | ((unsigned)f2b(v[3])<<16);
    u32x2 pk; pk.x=lo; pk.y=hi;
    *(u32x2*)&xb[row][f4*4] = pk;
  }
  const int w=tid>>6, lane=tid&63, c=lane&15, quad=lane>>4;
  __syncthreads();
  #pragma unroll
  for (int jj=0;jj<2;jj++){
    f32x4 acc[4][3];
    #pragma unroll
    for (int Mt=0;Mt<4;Mt++)
      #pragma unroll
      for (int g=0;g<3;g++) acc[Mt][g]=(f32x4){0.f,0.f,0.f,0.f};
    #pragma unroll
    for (int Kt=0;Kt<8;Kt++){
      bf16x8 a0=*(const bf16x8*)&xb[c][Kt*32+quad*8];
      bf16x8 a1=*(const bf16x8*)&xb[16+c][Kt*32+quad*8];
      bf16x8 a2=*(const bf16x8*)&xb[32+c][Kt*32+quad*8];
      bf16x8 a3=*(const bf16x8*)&xb[48+c][Kt*32+quad*8];
      #pragma unroll
      for (int g=0;g<3;g++){
        bf16x8 bfr=*(const bf16x8*)(W + (w*96+(jj*3+g)*16+c)*256 + Kt*32 + quad*8);
        acc[0][g]=mfma16(a0,bfr,acc[0][g]);
        acc[1][g]=mfma16(a1,bfr,acc[1][g]);
        acc[2][g]=mfma16(a2,bfr,acc[2][g]);
        acc[3][g]=mfma16(a3,bfr,acc[3][g]);
      }
    }
    float bv[3];
    #pragma unroll
    for (int g=0;g<3;g++) bv[g]=bias[w*96+(jj*3+g)*16+c];
    #pragma unroll
    for (int Mt=0;Mt<4;Mt++){
      int tp=Mt>>1, smh=Mt&1;
      unsigned d[6];
      #pragma unroll
      for (int k=0;k<6;k++){
        int s0=2*k, s1=2*k+1;
        int r0=s0/3, g0=s0%3, r1=s1/3, g1=s1%3;
        unsigned lo=f2b(acc[Mt][g0][r0]+bv[g0]);
        unsigned hi=f2b(acc[Mt][g1][r1]+bv[g1]);
        d[k]=lo|(hi<<16);
      }
      long block16 = (long)blk32*2 + smh;
      u16* dst = out + (block16*T + t0+tp)*TP + jj*6144 + (w*64+lane)*12;
      u32x2 s0v; s0v.x=d[0]; s0v.y=d[1];
      u32x2 s1v; s1v.x=d[2]; s1v.y=d[3];
      u32x2 s2v; s2v.x=d[4]; s2v.y=d[5];
      __builtin_nontemporal_store(s0v, (u32x2*)dst);
      __builtin_nontemporal_store(s1v, (u32x2*)(dst+4));
      __builtin_nontemporal_store(s2v, (u32x2*)(dst+8));
    }
  }
}

// ---------------------------------------------------------------------------
// Recurrent encoder scans (round-2 structure: 16 seqs/block, 172 blocks).
// Key change: __launch_bounds__(512,1) -> 256-VGPR cap (172 blocks = 1
// block/CU anyway, the old (512,2)/128-cap bought nothing and forced ~30
// W-fragment L2 reloads per wave per step). breg[32] holds nt=0..3 resident
// (128 VGPR); nt=4,5 streamed per-Kt (16 loads/step, each feeding 2 MFMAs,
// hidden under the 64 resident-weight MFMAs). Total demand ~220 < 256.
// ---------------------------------------------------------------------------
__global__ __launch_bounds__(512, 1) void k_enc_scan(
    const int* c_mask, const int* q_mask, const int* a1m, const int* a2m,
    const u16* cWhhP, const u16* qWhhP, const u16* aWhhP,
    const float* cBhh, const float* qBhh, const float* aBhh,
    const u16* gi_c, const u16* gi_q, const u16* gi_a1, const u16* gi_a2,
    u16* enc_hi, u16* enc_lo, float* enc_qf, float* enc_a1f, float* enc_a2f)
{
  __shared__ u16 hhi[16][264];
  __shared__ u16 hlo[16][264];
  __shared__ int idxs[16];
  int bid=blockIdx.x, tid=threadIdx.x;
  const int* msk; const u16* W; const float* bhh; const u16* gi; int T, seq0, mode;
  u16 *ohi=0, *olo=0; float* of=0;
  if (bid<160){ msk=c_mask; W=cWhhP; bhh=cBhh; gi=gi_c+(long)bid*SLEN*TP; T=SLEN; seq0=bid*16; mode=0; ohi=enc_hi; olo=enc_lo; }
  else if (bid<164){ int e=bid-160; msk=q_mask; W=qWhhP; bhh=qBhh; gi=gi_q+(long)e*QLEN*TP; T=QLEN; seq0=e*16; mode=1; of=enc_qf; }
  else if (bid<168){ int e=bid-164; msk=a1m; W=aWhhP; bhh=aBhh; gi=gi_a1+(long)e*ALEN*TP; T=ALEN; seq0=e*16; mode=1; of=enc_a1f; }
  else             { int e=bid-168; msk=a2m; W=aWhhP; bhh=aBhh; gi=gi_a2+(long)e*ALEN*TP; T=ALEN; seq0=e*16; mode=1; of=enc_a2f; }
  if (tid<16){
    int len=0; const int* mr=msk+(seq0+tid)*T;
    for (int t=0;t<T;t++) len += (mr[t]==0);
    int id=len-1; if(id<0)id=0; if(id>T-1)id=T-1; idxs[tid]=id;
  }
  for (int i=tid;i<16*264;i+=512){ ((u16*)hhi)[i]=0; ((u16*)hlo)[i]=0; }
  const int w=tid>>6, lane=tid&63, c=lane&15, quad=lane>>4;
  float biasv[6];
  #pragma unroll
  for (int nt=0;nt<6;nt++) biasv[nt]=bhh[w*96+nt*16+c];
  uint4 breg[32];           // nt = 0..3 resident
  #pragma unroll
  for (int nt=0;nt<4;nt++)
    #pragma unroll
    for (int Kt=0;Kt<8;Kt++)
      breg[nt*8+Kt] = *(const uint4*)(W + (w*96+nt*16+c)*256 + Kt*32 + quad*8);
  const u16* W4 = W + (w*96+64+c)*256 + quad*8;   // nt=4 streamed
  const u16* W5 = W + (w*96+80+c)*256 + quad*8;   // nt=5 streamed
  float hreg[8];
  #pragma unroll
  for (int i=0;i<8;i++) hreg[i]=0.f;
  const u16* gp = gi + (w*64+lane)*12;
  u32x2 pA0=*(const u32x2*)(gp),      pA1=*(const u32x2*)(gp+4),    pA2=*(const u32x2*)(gp+8);
  u32x2 pA3=*(const u32x2*)(gp+6144), pA4=*(const u32x2*)(gp+6148), pA5=*(const u32x2*)(gp+6152);
  __syncthreads();
  int idxr[4];
  #pragma unroll
  for (int r=0;r<4;r++) idxr[r]=idxs[quad*4+r];

  for (int t=0;t<T;t++){
    u32x2 pB0,pB1,pB2,pB3,pB4,pB5;
    bool pf=(t+1<T);
    if (pf){
      const u16* gn = gp + (long)(t+1)*TP;
      pB0=*(const u32x2*)(gn);      pB1=*(const u32x2*)(gn+4);    pB2=*(const u32x2*)(gn+8);
      pB3=*(const u32x2*)(gn+6144); pB4=*(const u32x2*)(gn+6148); pB5=*(const u32x2*)(gn+6152);
    }
    f32x4 acc[6];
    #pragma unroll
    for (int nt=0;nt<6;nt++) acc[nt]=(f32x4){0.f,0.f,0.f,0.f};
    #pragma unroll
    for (int Kt=0;Kt<8;Kt++){
      bf16x8 ahi_=*(const bf16x8*)&hhi[c][Kt*32+quad*8];
      bf16x8 alo_=*(const bf16x8*)&hlo[c][Kt*32+quad*8];
      bf16x8 b4=*(const bf16x8*)(W4 + Kt*32);
      bf16x8 b5=*(const bf16x8*)(W5 + Kt*32);
      #pragma unroll
      for (int nt=0;nt<4;nt++){
        acc[nt]=mfma16(ahi_,*(const bf16x8*)&breg[nt*8+Kt],acc[nt]);
        acc[nt]=mfma16(alo_,*(const bf16x8*)&breg[nt*8+Kt],acc[nt]);
      }
      acc[4]=mfma16(ahi_,b4,acc[4]); acc[4]=mfma16(alo_,b4,acc[4]);
      acc[5]=mfma16(ahi_,b5,acc[5]); acc[5]=mfma16(alo_,b5,acc[5]);
    }
    unsigned pd[12];
    *(u32x2*)&pd[0]=pA0; *(u32x2*)&pd[2]=pA1; *(u32x2*)&pd[4]=pA2;
    *(u32x2*)&pd[6]=pA3; *(u32x2*)&pd[8]=pA4; *(u32x2*)&pd[10]=pA5;
    #pragma unroll
    for (int r=0;r<4;r++){
      int m=quad*4+r;
      #pragma unroll
      for (int jj=0;jj<2;jj++){
        int j=w*32+jj*16+c;
        int ib=r*3;   // slot within jj region; words at pd[jj*6 + ...]
        float ir = b2f((u16)((pd[jj*6+(ib>>1)]     >> ((ib&1)*16)) & 0xffffu));
        float iz = b2f((u16)((pd[jj*6+((ib+1)>>1)] >> (((ib+1)&1)*16)) & 0xffffu));
        float in_= b2f((u16)((pd[jj*6+((ib+2)>>1)] >> (((ib+2)&1)*16)) & 0xffffu));
        float hr=acc[jj*3+0][r]+biasv[jj*3+0];
        float hz=acc[jj*3+1][r]+biasv[jj*3+1];
        float hn=acc[jj*3+2][r]+biasv[jj*3+2];
        float rr=sigm(ir+hr), zz=sigm(iz+hz), nn=tanh_(in_+rr*hn);
        float ho=hreg[r*2+jj];
        float hnew=(1.f-zz)*nn+zz*ho;
        hreg[r*2+jj]=hnew;
        u16 hi_=f2b(hnew); u16 lo_=f2b(hnew-b2f(hi_));
        hhi[m][j]=hi_; hlo[m][j]=lo_;
        if (t==idxr[r]){
          long o=(long)(seq0+m)*256+j;
          if (mode==0){ ohi[o]=hi_; olo[o]=lo_; }
          else of[o]=hnew;
        }
      }
    }
    __syncthreads();
    pA0=pB0; pA1=pB1; pA2=pB2; pA3=pB3; pA4=pB4; pA5=pB5;
  }
}

// ---------------------------------------------------------------------------
// gi_attn packed fp32: WG = (b-block of 16, sentence s). 160 WGs + init WG.
// Slot: gi_attn[(bblk*40+s)*TP + (w*64+lane)*24 + (r*2+jj)*3+gate]
// ---------------------------------------------------------------------------
__global__ __launch_bounds__(512, 2) void k_gi(
    const u16* enc_hi, const u16* enc_lo, const u16* tWihP, const float* tBih,
    float* gi_attn, const float* enc_qf, float* mem_f)
{
  int bid=blockIdx.x, tid=threadIdx.x;
  if (bid==160){ for (int i=tid;i<64*256;i+=512) mem_f[i]=enc_qf[i]; return; }
  __shared__ u16 ahi[16][264];
  __shared__ u16 alo[16][264];
  int bblk=bid/40, s=bid-bblk*40, b0=bblk*16;
  {
    int row=tid>>5, ch=tid&31;
    long seq=(long)(b0+row)*NSENT + s;
    *(uint4*)((char*)&ahi[row][0]+ch*16) = *((const uint4*)(enc_hi+seq*256)+ch);
    *(uint4*)((char*)&alo[row][0]+ch*16) = *((const uint4*)(enc_lo+seq*256)+ch);
  }
  const int w=tid>>6, lane=tid&63, c=lane&15, quad=lane>>4;
  f32x4 acc[6];
  #pragma unroll
  for (int nt=0;nt<6;nt++) acc[nt]=(f32x4){0.f,0.f,0.f,0.f};
  __syncthreads();
  #pragma unroll
  for (int Kt=0;Kt<8;Kt++){
    bf16x8 a=*(const bf16x8*)&ahi[c][Kt*32+quad*8];
    #pragma unroll
    for (int nt=0;nt<6;nt++){
      bf16x8 bfr=*(const bf16x8*)(tWihP + (w*96+nt*16+c)*256 + Kt*32 + quad*8);
      acc[nt]=mfma16(a,bfr,acc[nt]);
    }
  }
  #pragma unroll
  for (int Kt=0;Kt<8;Kt++){
    bf16x8 a=*(const bf16x8*)&alo[c][Kt*32+quad*8];
    #pragma unroll
    for (int nt=0;nt<6;nt++){
      bf16x8 bfr=*(const bf16x8*)(tWihP + (w*96+nt*16+c)*256 + Kt*32 + quad*8);
      acc[nt]=mfma16(a,bfr,acc[nt]);
    }
  }
  float biasv[6];
  #pragma unroll
  for (int nt=0;nt<6;nt++) biasv[nt]=tBih[w*96+nt*16+c];
  float* dst = gi_attn + ((long)(bblk*40+s))*TP + (w*64+lane)*SLOT;
  #pragma unroll
  for (int d=0;d<6;d++){
    float4 v;
    #pragma unroll
    for (int e=0;e<4;e++){
      int idx=4*d+e;
      int r=idx/6, rem=idx%6, jj=rem/3, g=rem%3;
      ((float*)&v)[e]=acc[jj*3+g][r]+biasv[jj*3+g];
    }
    *(float4*)(dst+4*d)=v;
  }
}

// ---------------------------------------------------------------------------
// Gate precompute (episode-invariant chunks {ct,q,ct*q,|ct-q|}).
// ---------------------------------------------------------------------------
__global__ __launch_bounds__(512, 1) void k_gatepre(
    const u16* enc_hi, const u16* enc_lo, const float* enc_qf,
    const u16* W1, const float* b1, float* partial)
{
  __shared__ float ctf[32][257];
  __shared__ float qvf[32][257];
  __shared__ u16 ab[32][264];
  int bid=blockIdx.x, tid=threadIdx.x, seq0=bid*32;
  #pragma unroll
  for (int p=0;p<16;p++){
    int i=p*512+tid; int row=i>>8, j=i&255;
    int grow=seq0+row; int b=grow/NSENT;
    ctf[row][j]=b2f(enc_hi[(long)grow*256+j])+b2f(enc_lo[(long)grow*256+j]);
    qvf[row][j]=enc_qf[b*256+j];
  }
  const int w=tid>>6, lane=tid&63, c=lane&15, quad=lane>>4;
  f32x4 acc[2][2];
  #pragma unroll
  for (int nt=0;nt<2;nt++){
    float bv=b1[(w*2+nt)*16+c];
    acc[0][nt]=(f32x4){bv,bv,bv,bv}; acc[1][nt]=acc[0][nt];
  }
  const int chl[4]={0,2,3,5};
  for (int ci=0; ci<4; ci++){
    int ch=chl[ci];
    __syncthreads();
    #pragma unroll
    for (int p=0;p<16;p++){
      int i=p*512+tid; int row=i>>8, j=i&255;
      float ct=ctf[row][j], qv=qvf[row][j];
      float v;
      if      (ch==0) v=ct;
      else if (ch==2) v=qv;
      else if (ch==3) v=ct*qv;
      else            v=fabsf(ct-qv);
      ab[row][j]=f2b(v);
    }
    __syncthreads();
    #pragma unroll
    for (int Kt=0;Kt<8;Kt++){
      bf16x8 a0=*(const bf16x8*)&ab[c][Kt*32+quad*8];
      bf16x8 a1=*(const bf16x8*)&ab[16+c][Kt*32+quad*8];
      #pragma unroll
      for (int nt=0;nt<2;nt++){
        int n=(w*2+nt)*16+c;
        bf16x8 bfr=*(const bf16x8*)(W1 + (long)n*1792 + ch*256 + Kt*32 + quad*8);
        acc[0][nt]=mfma16(a0,bfr,acc[0][nt]);
        acc[1][nt]=mfma16(a1,bfr,acc[1][nt]);
      }
    }
  }
  #pragma unroll
  for (int Mt=0;Mt<2;Mt++)
    #pragma unroll
    for (int nt=0;nt<2;nt++)
      #pragma unroll
      for (int r=0;r<4;r++)
        partial[(long)(seq0+Mt*16+quad*4+r)*256 + (w*2+nt)*16+c] = acc[Mt][nt][r];
}

// ---------------------------------------------------------------------------
// Per-episode gate: chunks {mem, ct*mem, |ct-mem|} + partial -> g.
// ---------------------------------------------------------------------------
__global__ __launch_bounds__(512, 1) void k_gate(
    const u16* enc_hi, const u16* enc_lo, const float* mem_f,
    const float* partial, const u16* W1, const float* W2, const float* b2v, float* g)
{
  __shared__ float ctf[32][257];
  __shared__ float mvf[32][257];
  __shared__ u16 ab[32][264];
  __shared__ float pl[32][8];
  int bid=blockIdx.x, tid=threadIdx.x, seq0=bid*32;
  #pragma unroll
  for (int p=0;p<16;p++){
    int i=p*512+tid; int row=i>>8, j=i&255;
    int grow=seq0+row; int b=grow/NSENT;
    ctf[row][j]=b2f(enc_hi[(long)grow*256+j])+b2f(enc_lo[(long)grow*256+j]);
    mvf[row][j]=mem_f[b*256+j];
  }
  const int w=tid>>6, lane=tid&63, c=lane&15, quad=lane>>4;
  f32x4 acc[2][2];
  float w2v[2];
  #pragma unroll
  for (int nt=0;nt<2;nt++){
    int n=(w*2+nt)*16+c;
    w2v[nt]=W2[n];
    #pragma unroll
    for (int Mt=0;Mt<2;Mt++)
      #pragma unroll
      for (int r=0;r<4;r++)
        acc[Mt][nt][r]=partial[(long)(seq0+Mt*16+quad*4+r)*256 + n];
  }
  const int chl[3]={1,4,6};
  for (int ci=0; ci<3; ci++){
    int ch=chl[ci];
    __syncthreads();
    #pragma unroll
    for (int p=0;p<16;p++){
      int i=p*512+tid; int row=i>>8, j=i&255;
      float ct=ctf[row][j], mv=mvf[row][j];
      float v;
      if      (ch==1) v=mv;
      else if (ch==4) v=ct*mv;
      else            v=fabsf(ct-mv);
      ab[row][j]=f2b(v);
    }
    __syncthreads();
    #pragma unroll
    for (int Kt=0;Kt<8;Kt++){
      bf16x8 a0=*(const bf16x8*)&ab[c][Kt*32+quad*8];
      bf16x8 a1=*(const bf16x8*)&ab[16+c][Kt*32+quad*8];
      #pragma unroll
      for (int nt=0;nt<2;nt++){
        int n=(w*2+nt)*16+c;
        bf16x8 bfr=*(const bf16x8*)(W1 + (long)n*1792 + ch*256 + Kt*32 + quad*8);
        acc[0][nt]=mfma16(a0,bfr,acc[0][nt]);
        acc[1][nt]=mfma16(a1,bfr,acc[1][nt]);
      }
    }
  }
  float pm[8];
  #pragma unroll
  for (int i=0;i<8;i++){
    int Mt=i>>2, r=i&3;
    float s=0.f;
    #pragma unroll
    for (int nt=0;nt<2;nt++) s += tanh_(acc[Mt][nt][r])*w2v[nt];
    pm[i]=s;
  }
  #pragma unroll
  for (int off=1;off<16;off<<=1)
    #pragma unroll
    for (int i=0;i<8;i++) pm[i]+=__shfl_xor(pm[i],off,64);
  if (c==0){
    #pragma unroll
    for (int i=0;i<8;i++){ int m=(i>>2)*16+quad*4+(i&3); pl[m][w]=pm[i]; }
  }
  __syncthreads();
  if (tid<32){
    float s=b2v[0];
    #pragma unroll
    for (int ww=0;ww<8;ww++) s+=pl[tid][ww];
    g[seq0+tid]=sigm(s);
  }
}

// ---------------------------------------------------------------------------
// Episodic scan: 4 WGs x 16 batch rows. (512,1) -> 256-VGPR cap: breg[32]
// resident (nt 0..3) + nt4/5 streamed per-Kt (L2-hot: 4 blocks share tWhh').
// Single-buffer pA loaded after the barrier (hidden under next step's MFMAs).
// ---------------------------------------------------------------------------
__global__ __launch_bounds__(512, 1) void k_scan(
    const u16* tWhhP, const float* tBhh,
    const float* gi_attn, const float* g,
    float* mem_f, const u16* mWihP, const u16* mWhhP,
    const float* mBih, const float* mBhh)
{
  __shared__ u16 hb[16][264];
  __shared__ u16 mhi[16][264];
  __shared__ u16 mlo[16][264];
  __shared__ float memfl[16][256];
  __shared__ float gl[16][40];
  int bid=blockIdx.x, tid=threadIdx.x, b0=bid*16;
  const int w=tid>>6, lane=tid&63, c=lane&15, quad=lane>>4;
  for (int i=tid;i<16*264;i+=512){ ((u16*)hb)[i]=0; }
  for (int i=tid;i<4096;i+=512){
    int m=i>>8, j=i&255;
    float v=mem_f[(b0+m)*256+j]; memfl[m][j]=v;
    u16 hi_=f2b(v); mhi[m][j]=hi_; mlo[m][j]=f2b(v-b2f(hi_));
  }
  for (int i=tid;i<640;i+=512){ int m=i/40, s=i-m*40; gl[m][s]=g[(b0+m)*40+s]; }
  float biasv[6];
  #pragma unroll
  for (int nt=0;nt<6;nt++) biasv[nt]=tBhh[w*96+nt*16+c];
  uint4 breg[32];           // nt = 0..3 resident
  #pragma unroll
  for (int nt=0;nt<4;nt++)
    #pragma unroll
    for (int Kt=0;Kt<8;Kt++)
      breg[nt*8+Kt] = *(const uint4*)(tWhhP + (w*96+nt*16+c)*256 + Kt*32 + quad*8);
  const u16* W4 = tWhhP + (w*96+64+c)*256 + quad*8;
  const u16* W5 = tWhhP + (w*96+80+c)*256 + quad*8;
  float hreg[8];
  #pragma unroll
  for (int i=0;i<8;i++) hreg[i]=0.f;
  const float* gp = gi_attn + ((long)bid*NSENT)*TP + (w*64+lane)*SLOT;
  float4 pA[6];
  #pragma unroll
  for (int d=0;d<6;d++) pA[d]=*(const float4*)(gp+4*d);
  __syncthreads();

  for (int s=0;s<NSENT;s++){
    f32x4 acc[6];
    #pragma unroll
    for (int nt=0;nt<6;nt++) acc[nt]=(f32x4){0.f,0.f,0.f,0.f};
    #pragma unroll
    for (int Kt=0;Kt<8;Kt++){
      bf16x8 a=*(const bf16x8*)&hb[c][Kt*32+quad*8];
      bf16x8 b4=*(const bf16x8*)(W4 + Kt*32);
      bf16x8 b5=*(const bf16x8*)(W5 + Kt*32);
      #pragma unroll
      for (int nt=0;nt<4;nt++) acc[nt]=mfma16(a,*(const bf16x8*)&breg[nt*8+Kt],acc[nt]);
      acc[4]=mfma16(a,b4,acc[4]);
      acc[5]=mfma16(a,b5,acc[5]);
    }
    const float* pf32 = (const float*)&pA[0];
    #pragma unroll
    for (int r=0;r<4;r++){
      int m=quad*4+r;
      float gv = gl[m][s];
      #pragma unroll
      for (int jj=0;jj<2;jj++){
        int j=w*32+jj*16+c;
        int ib=(r*2+jj)*3;
        float ir=pf32[ib], iz=pf32[ib+1], in_=pf32[ib+2];
        float hr=acc[jj*3+0][r]+biasv[jj*3+0];
        float hz=acc[jj*3+1][r]+biasv[jj*3+1];
        float hn=acc[jj*3+2][r]+biasv[jj*3+2];
        float rr=sigm(ir+hr), zz=sigm(iz+hz), nn=tanh_(in_+rr*hn);
        float ho=hreg[r*2+jj];
        float hc=(1.f-zz)*nn+zz*ho;
        float hnew=gv*hc+(1.f-gv)*ho;
        hreg[r*2+jj]=hnew;
        hb[m][j]=f2b(hnew);
      }
    }
    __syncthreads();
    if (s+1<NSENT){
      const float* gn = gp + (long)(s+1)*TP;
      #pragma unroll
      for (int d=0;d<6;d++) pA[d]=*(const float4*)(gn+4*d);
    }
  }
  // memory GRU, pi layout: ai = e@mWih'^T, ah = mem(hi+lo)@mWhh'^T
  f32x4 ai[6], ah[6];
  #pragma unroll
  for (int nt=0;nt<6;nt++){ ai[nt]=(f32x4){0.f,0.f,0.f,0.f}; ah[nt]=ai[nt]; }
  #pragma unroll
  for (int Kt=0;Kt<8;Kt++){
    bf16x8 a=*(const bf16x8*)&hb[c][Kt*32+quad*8];
    #pragma unroll
    for (int nt=0;nt<6;nt++){
      bf16x8 bfr=*(const bf16x8*)(mWihP + (w*96+nt*16+c)*256 + Kt*32 + quad*8);
      ai[nt]=mfma16(a,bfr,ai[nt]);
    }
  }
  #pragma unroll
  for (int Kt=0;Kt<8;Kt++){
    bf16x8 a=*(const bf16x8*)&mhi[c][Kt*32+quad*8];
    #pragma unroll
    for (int nt=0;nt<6;nt++){
      bf16x8 bfr=*(const bf16x8*)(mWhhP + (w*96+nt*16+c)*256 + Kt*32 + quad*8);
      ah[nt]=mfma16(a,bfr,ah[nt]);
    }
  }
  #pragma unroll
  for (int Kt=0;Kt<8;Kt++){
    bf16x8 a=*(const bf16x8*)&mlo[c][Kt*32+quad*8];
    #pragma unroll
    for (int nt=0;nt<6;nt++){
      bf16x8 bfr=*(const bf16x8*)(mWhhP + (w*96+nt*16+c)*256 + Kt*32 + quad*8);
      ah[nt]=mfma16(a,bfr,ah[nt]);
    }
  }
  float bih6[6], bhh6[6];
  #pragma unroll
  for (int nt=0;nt<6;nt++){ bih6[nt]=mBih[w*96+nt*16+c]; bhh6[nt]=mBhh[w*96+nt*16+c]; }
  #pragma unroll
  for (int r=0;r<4;r++){
    int m=quad*4+r;
    #pragma unroll
    for (int jj=0;jj<2;jj++){
      int j=w*32+jj*16+c;
      float ir=ai[jj*3+0][r]+bih6[jj*3+0];
      float iz=ai[jj*3+1][r]+bih6[jj*3+1];
      float in_=ai[jj*3+2][r]+bih6[jj*3+2];
      float hr=ah[jj*3+0][r]+bhh6[jj*3+0];
      float hz=ah[jj*3+1][r]+bhh6[jj*3+1];
      float hn=ah[jj*3+2][r]+bhh6[jj*3+2];
      float rr=sigm(ir+hr), zz=sigm(iz+hz), nn=tanh_(in_+rr*hn);
      float mo=memfl[m][j];
      mem_f[(b0+m)*256+j]=(1.f-zz)*nn+zz*mo;
    }
  }
}

// ---------------------------------------------------------------------------
// Final head, all fp32.
// ---------------------------------------------------------------------------
__global__ void k_final(const float* mem_f, const float* a1f, const float* a2f,
    const float* W1o, const float* b1o, const float* W2o, const float* b2o, float* outp)
{
  __shared__ float af[768];
  __shared__ float tl[256];
  __shared__ float lg[2];
  int b=blockIdx.x, tid=threadIdx.x;
  af[tid]     = mem_f[b*256+tid];
  af[256+tid] = a1f[b*256+tid];
  af[512+tid] = a2f[b*256+tid];
  __syncthreads();
  float s=b1o[tid];
  const float* wr=W1o + (long)tid*768;
  for (int k=0;k<768;k++) s += af[k]*wr[k];
  tl[tid]=tanh_(s);
  __syncthreads();
  if (tid<2){
    float l=b2o[tid];
    const float* w2=W2o + tid*256;
    for (int k=0;k<256;k++) l += tl[k]*w2[k];
    lg[tid]=l;
  }
  __syncthreads();
  if (tid==0){
    float m=fmaxf(lg[0],lg[1]);
    float e0=__expf(lg[0]-m), e1=__expf(lg[1]-m);
    float inv=1.f/(e0+e1);
    outp[b*2]=e0*inv; outp[b*2+1]=e1*inv;
  }
}

// ---------------------------------------------------------------------------
extern "C" void kernel_launch(void* const* d_in, const int* in_sizes, int n_in,
                              void* d_out, int out_size, void* d_ws, size_t ws_size,
                              hipStream_t stream) {
  const int* c_p   = (const int*)d_in[0];
  const int* c_m   = (const int*)d_in[1];
  const int* q_p   = (const int*)d_in[2];
  const int* q_m   = (const int*)d_in[3];
  const int* a1p   = (const int*)d_in[4];
  const int* a1m   = (const int*)d_in[5];
  const int* a2p   = (const int*)d_in[6];
  const int* a2m   = (const int*)d_in[7];
  const float* embed = (const float*)d_in[8];
  const float* cWih=(const float*)d_in[9],  *cWhh=(const float*)d_in[10], *cbih=(const float*)d_in[11], *cbhh=(const float*)d_in[12];
  const float* qWih=(const float*)d_in[13], *qWhh=(const float*)d_in[14], *qbih=(const float*)d_in[15], *qbhh=(const float*)d_in[16];
  const float* aWih=(const float*)d_in[17], *aWhh=(const float*)d_in[18], *abih=(const float*)d_in[19], *abhh=(const float*)d_in[20];
  const float* tWih=(const float*)d_in[21], *tWhh=(const float*)d_in[22], *tbih=(const float*)d_in[23], *tbhh=(const float*)d_in[24];
  const float* mWih=(const float*)d_in[25], *mWhh=(const float*)d_in[26], *mbih=(const float*)d_in[27], *mbhh=(const float*)d_in[28];
  const float* gW1=(const float*)d_in[29], *gb1=(const float*)d_in[30], *gW2=(const float*)d_in[31], *gb2=(const float*)d_in[32];
  const float* oW1=(const float*)d_in[33], *ob1=(const float*)d_in[34], *oW2=(const float*)d_in[35], *ob2=(const float*)d_in[36];

  char* ws = (char*)d_ws;
  size_t off = 0;
  u16* P[10];
  for (int i=0;i<10;i++){ P[i]=(u16*)(ws+off); off+=393216; }
  u16* PgW1 =(u16*)(ws+off); off+=917504;
  float* B[10];
  for (int i=0;i<10;i++){ B[i]=(float*)(ws+off); off+=3072; }
  u16* gi_c =(u16*)(ws+off); off+=(size_t)160*SLEN*TP*2;   // 118 MB
  u16* gi_q =(u16*)(ws+off); off+=(size_t)4*QLEN*TP*2;
  u16* gi_a1=(u16*)(ws+off); off+=(size_t)4*ALEN*TP*2;
  u16* gi_a2=(u16*)(ws+off); off+=(size_t)4*ALEN*TP*2;
  u16* enc_hi=(u16*)(ws+off); off+=(size_t)SCTX*256*2;
  u16* enc_lo=(u16*)(ws+off); off+=(size_t)SCTX*256*2;
  float* enc_qf =(float*)(ws+off); off+=64*256*4;
  float* enc_a1f=(float*)(ws+off); off+=64*256*4;
  float* enc_a2f=(float*)(ws+off); off+=64*256*4;
  float* mem_f  =(float*)(ws+off); off+=64*256*4;
  float* gi_attn=(float*)(ws+off); off+=(size_t)160*TP*4;  // 7.9 MB
  float* partial=(float*)(ws+off); off+=(size_t)SCTX*256*4;
  float* gbuf   =(float*)(ws+off); off+=SCTX*4;

  k_prep<<<4751, 512, 0, stream>>>(cWih,cWhh,qWih,qWhh,aWih,aWhh,tWih,tWhh,mWih,mWhh,gW1,
      cbih,cbhh,qbih,qbhh,abih,abhh,tbih,tbhh,mbih,mbhh,
      P[0],P[1],P[2],P[3],P[4],P[5],P[6],P[7],P[8],P[9], PgW1,
      B[0],B[1],B[2],B[3],B[4],B[5],B[6],B[7],B[8],B[9]);

  k_xproj<<<1244, 512, 0, stream>>>(c_p,q_p,a1p,a2p, embed,
      P[0],P[2],P[4], B[0],B[2],B[4], gi_c,gi_q,gi_a1,gi_a2);

  k_enc_scan<<<172, 512, 0, stream>>>(c_m,q_m,a1m,a2m,
      P[1],P[3],P[5], B[1],B[3],B[5], gi_c,gi_q,gi_a1,gi_a2,
      enc_hi,enc_lo, enc_qf,enc_a1f,enc_a2f);

  k_gi<<<161, 512, 0, stream>>>(enc_hi,enc_lo, P[6], B[6], gi_attn, enc_qf, mem_f);

  k_gatepre<<<80, 512, 0, stream>>>(enc_hi,enc_lo, enc_qf, PgW1, gb1, partial);

  for (int ep=0; ep<3; ep++){
    k_gate<<<80, 512, 0, stream>>>(enc_hi,enc_lo, mem_f, partial, PgW1, gW2, gb2, gbuf);
    k_scan<<<4, 512, 0, stream>>>(P[7], B[7], gi_attn, gbuf, mem_f, P[8], P[9], B[8], B[9]);
  }

  k_final<<<64, 256, 0, stream>>>(mem_f, enc_a1f, enc_a2f, oW1, ob1, oW2, ob2, (float*)d_out);
}

// Round 7
// 932.199 us; speedup vs baseline: 1.3641x; 1.3641x over previous
//
#include <hip/hip_runtime.h>

typedef unsigned short u16;
typedef __bf16 bf16x8 __attribute__((ext_vector_type(8)));
typedef float f32x4 __attribute__((ext_vector_type(4)));
typedef float f32x4v __attribute__((ext_vector_type(4)));
typedef unsigned int u32x2 __attribute__((ext_vector_type(2)));

#define NSENT 40
#define SLEN 30
#define QLEN 20
#define ALEN 12
#define SCTX 2560
#define SLOT 24              // u16 (or fp32) values per lane-slot
#define TP 12288             // 512*24 elements per (block,t) plane

__device__ __forceinline__ float b2f(u16 u){ union{float f; unsigned i;} v; v.i = ((unsigned)u)<<16; return v.f; }
__device__ __forceinline__ u16 f2b(float f){ union{float f; unsigned u;} v; v.f=f; unsigned u=v.u; u += ((u>>16)&1u) + 0x7fffu; return (u16)(u>>16); }
__device__ __forceinline__ float sigm(float x){ return __builtin_amdgcn_rcpf(1.f + __expf(-x)); }
__device__ __forceinline__ float tanh_(float x){
  float a = fminf(fmaxf(2.f*x, -30.f), 30.f);
  float e = __expf(a);
  return 1.f - 2.f*__builtin_amdgcn_rcpf(e + 1.f);
}
__device__ __forceinline__ f32x4 mfma16(bf16x8 a, bf16x8 b, f32x4 c){
  return __builtin_amdgcn_mfma_f32_16x16x32_bf16(a, b, c, 0, 0, 0);
}

// ---------------------------------------------------------------------------
// Prep: pi-permute (n' = g16*48 + gate*16 + c <-> j = gate*256 + g16*16 + c)
// 10 weight mats -> bf16 P0..P9; gW1 plain bf16; 10 pi-permuted fp32 biases.
// ---------------------------------------------------------------------------
__global__ void k_prep(
    const float* cWih, const float* cWhh, const float* qWih, const float* qWhh,
    const float* aWih, const float* aWhh, const float* tWih, const float* tWhh,
    const float* mWih, const float* mWhh, const float* gW1,
    const float* cbih, const float* cbhh, const float* qbih, const float* qbhh,
    const float* abih, const float* abhh, const float* tbih, const float* tbhh,
    const float* mbih, const float* mbhh,
    u16* P0,u16* P1,u16* P2,u16* P3,u16* P4,u16* P5,u16* P6,u16* P7,u16* P8,u16* P9,
    u16* PgW1,
    float* B0,float* B1,float* B2,float* B3,float* B4,float* B5,float* B6,float* B7,
    float* B8,float* B9)
{
  int i = blockIdx.x*512 + threadIdx.x;   // 4751*512 = 2,432,512
  if (i < 1966080){
    int seg = i/196608; int e = i - seg*196608;
    int np = e>>8, k = e&255;
    int g16 = np/48, rem = np - g16*48, gate = rem>>4, cc = rem&15;
    int j = gate*256 + g16*16 + cc;
    const float* S; u16* D;
    switch(seg){
      case 0: S=cWih; D=P0; break; case 1: S=cWhh; D=P1; break;
      case 2: S=qWih; D=P2; break; case 3: S=qWhh; D=P3; break;
      case 4: S=aWih; D=P4; break; case 5: S=aWhh; D=P5; break;
      case 6: S=tWih; D=P6; break; case 7: S=tWhh; D=P7; break;
      case 8: S=mWih; D=P8; break; default: S=mWhh; D=P9; break;
    }
    D[e] = f2b(S[j*256 + k]);
  } else if (i < 2424832){
    int e = i - 1966080;
    PgW1[e] = f2b(gW1[e]);
  } else {
    int e = i - 2424832;                  // 7680 = 10*768
    int seg = e/768; int np = e - seg*768;
    int g16 = np/48, rem = np - g16*48, gate = rem>>4, cc = rem&15;
    int j = gate*256 + g16*16 + cc;
    const float* S; float* D;
    switch(seg){
      case 0: S=cbih; D=B0; break; case 1: S=cbhh; D=B1; break;
      case 2: S=qbih; D=B2; break; case 3: S=qbhh; D=B3; break;
      case 4: S=abih; D=B4; break; case 5: S=abhh; D=B5; break;
      case 6: S=tbih; D=B6; break; case 7: S=tbhh; D=B7; break;
      case 8: S=mbih; D=B8; break; default: S=mbhh; D=B9; break;
    }
    D[np] = S[j];
  }
}

// ---------------------------------------------------------------------------
// x-projections. 64 rows/block (32 seqs x 2 t); nt embed loads + nt gi stores
// keep the 393KB weight matrix L2-resident.
// gi plane layout: plane*TP + jj*6144 + (w8*64+lane)*12 + (r*3+g).
// ---------------------------------------------------------------------------
__global__ __launch_bounds__(512, 4) void k_xproj(
    const int* c_p, const int* q_p, const int* a1p, const int* a2p,
    const float* embed,
    const u16* cWihP, const u16* qWihP, const u16* aWihP,
    const float* cBih, const float* qBih, const float* aBih,
    u16* gi_c, u16* gi_q, u16* gi_a1, u16* gi_a2)
{
  __shared__ u16 xb[64][288];
  int bid=blockIdx.x, tid=threadIdx.x;
  const int* toks; const u16* W; const float* bias; u16* out; int T, blk32, t0;
  if (bid < 1200){ toks=c_p; W=cWihP; bias=cBih; out=gi_c; T=SLEN; blk32=bid/15; t0=(bid-blk32*15)*2; }
  else if (bid < 1220){ int e=bid-1200; toks=q_p; W=qWihP; bias=qBih; out=gi_q; T=QLEN; blk32=e/10; t0=(e-blk32*10)*2; }
  else if (bid < 1232){ int e=bid-1220; toks=a1p; W=aWihP; bias=aBih; out=gi_a1; T=ALEN; blk32=e/6; t0=(e-blk32*6)*2; }
  else               { int e=bid-1232; toks=a2p; W=aWihP; bias=aBih; out=gi_a2; T=ALEN; blk32=e/6; t0=(e-blk32*6)*2; }
  int seq0 = blk32*32;
  #pragma unroll
  for (int p=0;p<8;p++){
    int i=p*512+tid; int row=i>>6, f4=i&63;   // row wave-uniform
    int tp=row>>5, sm=row&31;
    int tok = toks[(seq0+sm)*T + t0+tp];
    f32x4v v = __builtin_nontemporal_load((const f32x4v*)(embed + (long)tok*256) + f4);
    unsigned lo = (unsigned)f2b(v[0]) | ((unsigned)f2b(v[1])<<16);
    unsigned hi = (unsigned)f2b(v[2]) | ((unsigned)f2b(v[3])<<16);
    u32x2 pk; pk.x=lo; pk.y=hi;
    *(u32x2*)&xb[row][f4*4] = pk;
  }
  const int w=tid>>6, lane=tid&63, c=lane&15, quad=lane>>4;
  __syncthreads();
  #pragma unroll
  for (int jj=0;jj<2;jj++){
    f32x4 acc[4][3];
    #pragma unroll
    for (int Mt=0;Mt<4;Mt++)
      #pragma unroll
      for (int g=0;g<3;g++) acc[Mt][g]=(f32x4){0.f,0.f,0.f,0.f};
    #pragma unroll
    for (int Kt=0;Kt<8;Kt++){
      bf16x8 a0=*(const bf16x8*)&xb[c][Kt*32+quad*8];
      bf16x8 a1=*(const bf16x8*)&xb[16+c][Kt*32+quad*8];
      bf16x8 a2=*(const bf16x8*)&xb[32+c][Kt*32+quad*8];
      bf16x8 a3=*(const bf16x8*)&xb[48+c][Kt*32+quad*8];
      #pragma unroll
      for (int g=0;g<3;g++){
        bf16x8 bfr=*(const bf16x8*)(W + (w*96+(jj*3+g)*16+c)*256 + Kt*32 + quad*8);
        acc[0][g]=mfma16(a0,bfr,acc[0][g]);
        acc[1][g]=mfma16(a1,bfr,acc[1][g]);
        acc[2][g]=mfma16(a2,bfr,acc[2][g]);
        acc[3][g]=mfma16(a3,bfr,acc[3][g]);
      }
    }
    float bv[3];
    #pragma unroll
    for (int g=0;g<3;g++) bv[g]=bias[w*96+(jj*3+g)*16+c];
    #pragma unroll
    for (int Mt=0;Mt<4;Mt++){
      int tp=Mt>>1, smh=Mt&1;
      unsigned d[6];
      #pragma unroll
      for (int k=0;k<6;k++){
        int s0=2*k, s1=2*k+1;
        int r0=s0/3, g0=s0%3, r1=s1/3, g1=s1%3;
        unsigned lo=f2b(acc[Mt][g0][r0]+bv[g0]);
        unsigned hi=f2b(acc[Mt][g1][r1]+bv[g1]);
        d[k]=lo|(hi<<16);
      }
      long block16 = (long)blk32*2 + smh;
      u16* dst = out + (block16*T + t0+tp)*TP + jj*6144 + (w*64+lane)*12;
      u32x2 s0v; s0v.x=d[0]; s0v.y=d[1];
      u32x2 s1v; s1v.x=d[2]; s1v.y=d[3];
      u32x2 s2v; s2v.x=d[4]; s2v.y=d[5];
      __builtin_nontemporal_store(s0v, (u32x2*)dst);
      __builtin_nontemporal_store(s1v, (u32x2*)(dst+4));
      __builtin_nontemporal_store(s2v, (u32x2*)(dst+8));
    }
  }
}

// ---------------------------------------------------------------------------
// Recurrent encoder scans (round-2 proven structure: 16 seqs/block, 172
// blocks, breg[48], double-buffered gi prefetch). Register-budget control:
// amdgpu_waves_per_eu(2,2) pins the allocator to the 2-waves/SIMD budget
// (256 VGPR) that one 512-thread WG/CU actually gives, and the >80KB LDS
// pad makes a second WG impossible so the occupancy heuristic cannot
// prefer a 128-reg allocation (rounds 3/5/6: allocator remats/spills
// whenever higher occupancy is theoretically possible).
// ---------------------------------------------------------------------------
__global__ __launch_bounds__(512) __attribute__((amdgpu_waves_per_eu(2,2)))
void k_enc_scan(
    const int* c_mask, const int* q_mask, const int* a1m, const int* a2m,
    const u16* cWhhP, const u16* qWhhP, const u16* aWhhP,
    const float* cBhh, const float* qBhh, const float* aBhh,
    const u16* gi_c, const u16* gi_q, const u16* gi_a1, const u16* gi_a2,
    u16* enc_hi, u16* enc_lo, float* enc_qf, float* enc_a1f, float* enc_a2f,
    int never)
{
  __shared__ u16 hhi[16][264];
  __shared__ u16 hlo[16][264];
  __shared__ int idxs[16];
  __shared__ float ldspad[16640];   // total LDS ~83.5KB -> max 1 WG/CU
  int bid=blockIdx.x, tid=threadIdx.x;
  if (never) ((volatile float*)ldspad)[tid] = 1.0f;
  const int* msk; const u16* W; const float* bhh; const u16* gi; int T, seq0, mode;
  u16 *ohi=0, *olo=0; float* of=0;
  if (bid<160){ msk=c_mask; W=cWhhP; bhh=cBhh; gi=gi_c+(long)bid*SLEN*TP; T=SLEN; seq0=bid*16; mode=0; ohi=enc_hi; olo=enc_lo; }
  else if (bid<164){ int e=bid-160; msk=q_mask; W=qWhhP; bhh=qBhh; gi=gi_q+(long)e*QLEN*TP; T=QLEN; seq0=e*16; mode=1; of=enc_qf; }
  else if (bid<168){ int e=bid-164; msk=a1m; W=aWhhP; bhh=aBhh; gi=gi_a1+(long)e*ALEN*TP; T=ALEN; seq0=e*16; mode=1; of=enc_a1f; }
  else             { int e=bid-168; msk=a2m; W=aWhhP; bhh=aBhh; gi=gi_a2+(long)e*ALEN*TP; T=ALEN; seq0=e*16; mode=1; of=enc_a2f; }
  if (tid<16){
    int len=0; const int* mr=msk+(seq0+tid)*T;
    for (int t=0;t<T;t++) len += (mr[t]==0);
    int id=len-1; if(id<0)id=0; if(id>T-1)id=T-1; idxs[tid]=id;
  }
  for (int i=tid;i<16*264;i+=512){ ((u16*)hhi)[i]=0; ((u16*)hlo)[i]=0; }
  const int w=tid>>6, lane=tid&63, c=lane&15, quad=lane>>4;
  float biasv[6];
  #pragma unroll
  for (int nt=0;nt<6;nt++) biasv[nt]=bhh[w*96+nt*16+c];
  uint4 breg[48];
  #pragma unroll
  for (int nt=0;nt<6;nt++)
    #pragma unroll
    for (int Kt=0;Kt<8;Kt++)
      breg[nt*8+Kt] = *(const uint4*)(W + (w*96+nt*16+c)*256 + Kt*32 + quad*8);
  float hreg[8];
  #pragma unroll
  for (int i=0;i<8;i++) hreg[i]=0.f;
  const u16* gp = gi + (w*64+lane)*12;
  u32x2 pA0=*(const u32x2*)(gp),      pA1=*(const u32x2*)(gp+4),    pA2=*(const u32x2*)(gp+8);
  u32x2 pA3=*(const u32x2*)(gp+6144), pA4=*(const u32x2*)(gp+6148), pA5=*(const u32x2*)(gp+6152);
  __syncthreads();
  int idxr[4];
  #pragma unroll
  for (int r=0;r<4;r++) idxr[r]=idxs[quad*4+r];

  for (int t=0;t<T;t++){
    u32x2 pB0,pB1,pB2,pB3,pB4,pB5;
    bool pf=(t+1<T);
    if (pf){
      const u16* gn = gp + (long)(t+1)*TP;
      pB0=*(const u32x2*)(gn);      pB1=*(const u32x2*)(gn+4);    pB2=*(const u32x2*)(gn+8);
      pB3=*(const u32x2*)(gn+6144); pB4=*(const u32x2*)(gn+6148); pB5=*(const u32x2*)(gn+6152);
    }
    f32x4 acc[6];
    #pragma unroll
    for (int nt=0;nt<6;nt++) acc[nt]=(f32x4){0.f,0.f,0.f,0.f};
    #pragma unroll
    for (int Kt=0;Kt<8;Kt++){
      bf16x8 a=*(const bf16x8*)&hhi[c][Kt*32+quad*8];
      #pragma unroll
      for (int nt=0;nt<6;nt++) acc[nt]=mfma16(a,*(const bf16x8*)&breg[nt*8+Kt],acc[nt]);
    }
    #pragma unroll
    for (int Kt=0;Kt<8;Kt++){
      bf16x8 a=*(const bf16x8*)&hlo[c][Kt*32+quad*8];
      #pragma unroll
      for (int nt=0;nt<6;nt++) acc[nt]=mfma16(a,*(const bf16x8*)&breg[nt*8+Kt],acc[nt]);
    }
    unsigned pd[12];
    *(u32x2*)&pd[0]=pA0; *(u32x2*)&pd[2]=pA1; *(u32x2*)&pd[4]=pA2;
    *(u32x2*)&pd[6]=pA3; *(u32x2*)&pd[8]=pA4; *(u32x2*)&pd[10]=pA5;
    #pragma unroll
    for (int r=0;r<4;r++){
      int m=quad*4+r;
      #pragma unroll
      for (int jj=0;jj<2;jj++){
        int j=w*32+jj*16+c;
        int ib=r*3;   // slot within jj region; words at pd[jj*6 + ...]
        float ir = b2f((u16)((pd[jj*6+(ib>>1)]     >> ((ib&1)*16)) & 0xffffu));
        float iz = b2f((u16)((pd[jj*6+((ib+1)>>1)] >> (((ib+1)&1)*16)) & 0xffffu));
        float in_= b2f((u16)((pd[jj*6+((ib+2)>>1)] >> (((ib+2)&1)*16)) & 0xffffu));
        float hr=acc[jj*3+0][r]+biasv[jj*3+0];
        float hz=acc[jj*3+1][r]+biasv[jj*3+1];
        float hn=acc[jj*3+2][r]+biasv[jj*3+2];
        float rr=sigm(ir+hr), zz=sigm(iz+hz), nn=tanh_(in_+rr*hn);
        float ho=hreg[r*2+jj];
        float hnew=(1.f-zz)*nn+zz*ho;
        hreg[r*2+jj]=hnew;
        u16 hi_=f2b(hnew); u16 lo_=f2b(hnew-b2f(hi_));
        hhi[m][j]=hi_; hlo[m][j]=lo_;
        if (t==idxr[r]){
          long o=(long)(seq0+m)*256+j;
          if (mode==0){ ohi[o]=hi_; olo[o]=lo_; }
          else of[o]=hnew;
        }
      }
    }
    __syncthreads();
    pA0=pB0; pA1=pB1; pA2=pB2; pA3=pB3; pA4=pB4; pA5=pB5;
  }
}

// ---------------------------------------------------------------------------
// gi_attn packed fp32: WG = (b-block of 16, sentence s). 160 WGs + init WG.
// Slot: gi_attn[(bblk*40+s)*TP + (w*64+lane)*24 + (r*2+jj)*3+gate]
// ---------------------------------------------------------------------------
__global__ __launch_bounds__(512, 2) void k_gi(
    const u16* enc_hi, const u16* enc_lo, const u16* tWihP, const float* tBih,
    float* gi_attn, const float* enc_qf, float* mem_f)
{
  int bid=blockIdx.x, tid=threadIdx.x;
  if (bid==160){ for (int i=tid;i<64*256;i+=512) mem_f[i]=enc_qf[i]; return; }
  __shared__ u16 ahi[16][264];
  __shared__ u16 alo[16][264];
  int bblk=bid/40, s=bid-bblk*40, b0=bblk*16;
  {
    int row=tid>>5, ch=tid&31;
    long seq=(long)(b0+row)*NSENT + s;
    *(uint4*)((char*)&ahi[row][0]+ch*16) = *((const uint4*)(enc_hi+seq*256)+ch);
    *(uint4*)((char*)&alo[row][0]+ch*16) = *((const uint4*)(enc_lo+seq*256)+ch);
  }
  const int w=tid>>6, lane=tid&63, c=lane&15, quad=lane>>4;
  f32x4 acc[6];
  #pragma unroll
  for (int nt=0;nt<6;nt++) acc[nt]=(f32x4){0.f,0.f,0.f,0.f};
  __syncthreads();
  #pragma unroll
  for (int Kt=0;Kt<8;Kt++){
    bf16x8 a=*(const bf16x8*)&ahi[c][Kt*32+quad*8];
    #pragma unroll
    for (int nt=0;nt<6;nt++){
      bf16x8 bfr=*(const bf16x8*)(tWihP + (w*96+nt*16+c)*256 + Kt*32 + quad*8);
      acc[nt]=mfma16(a,bfr,acc[nt]);
    }
  }
  #pragma unroll
  for (int Kt=0;Kt<8;Kt++){
    bf16x8 a=*(const bf16x8*)&alo[c][Kt*32+quad*8];
    #pragma unroll
    for (int nt=0;nt<6;nt++){
      bf16x8 bfr=*(const bf16x8*)(tWihP + (w*96+nt*16+c)*256 + Kt*32 + quad*8);
      acc[nt]=mfma16(a,bfr,acc[nt]);
    }
  }
  float biasv[6];
  #pragma unroll
  for (int nt=0;nt<6;nt++) biasv[nt]=tBih[w*96+nt*16+c];
  float* dst = gi_attn + ((long)(bblk*40+s))*TP + (w*64+lane)*SLOT;
  #pragma unroll
  for (int d=0;d<6;d++){
    float4 v;
    #pragma unroll
    for (int e=0;e<4;e++){
      int idx=4*d+e;
      int r=idx/6, rem=idx%6, jj=rem/3, g=rem%3;
      ((float*)&v)[e]=acc[jj*3+g][r]+biasv[jj*3+g];
    }
    *(float4*)(dst+4*d)=v;
  }
}

// ---------------------------------------------------------------------------
// Gate precompute (episode-invariant chunks {ct,q,ct*q,|ct-q|}).
// ---------------------------------------------------------------------------
__global__ __launch_bounds__(512, 1) void k_gatepre(
    const u16* enc_hi, const u16* enc_lo, const float* enc_qf,
    const u16* W1, const float* b1, float* partial)
{
  __shared__ float ctf[32][257];
  __shared__ float qvf[32][257];
  __shared__ u16 ab[32][264];
  int bid=blockIdx.x, tid=threadIdx.x, seq0=bid*32;
  #pragma unroll
  for (int p=0;p<16;p++){
    int i=p*512+tid; int row=i>>8, j=i&255;
    int grow=seq0+row; int b=grow/NSENT;
    ctf[row][j]=b2f(enc_hi[(long)grow*256+j])+b2f(enc_lo[(long)grow*256+j]);
    qvf[row][j]=enc_qf[b*256+j];
  }
  const int w=tid>>6, lane=tid&63, c=lane&15, quad=lane>>4;
  f32x4 acc[2][2];
  #pragma unroll
  for (int nt=0;nt<2;nt++){
    float bv=b1[(w*2+nt)*16+c];
    acc[0][nt]=(f32x4){bv,bv,bv,bv}; acc[1][nt]=acc[0][nt];
  }
  const int chl[4]={0,2,3,5};
  for (int ci=0; ci<4; ci++){
    int ch=chl[ci];
    __syncthreads();
    #pragma unroll
    for (int p=0;p<16;p++){
      int i=p*512+tid; int row=i>>8, j=i&255;
      float ct=ctf[row][j], qv=qvf[row][j];
      float v;
      if      (ch==0) v=ct;
      else if (ch==2) v=qv;
      else if (ch==3) v=ct*qv;
      else            v=fabsf(ct-qv);
      ab[row][j]=f2b(v);
    }
    __syncthreads();
    #pragma unroll
    for (int Kt=0;Kt<8;Kt++){
      bf16x8 a0=*(const bf16x8*)&ab[c][Kt*32+quad*8];
      bf16x8 a1=*(const bf16x8*)&ab[16+c][Kt*32+quad*8];
      #pragma unroll
      for (int nt=0;nt<2;nt++){
        int n=(w*2+nt)*16+c;
        bf16x8 bfr=*(const bf16x8*)(W1 + (long)n*1792 + ch*256 + Kt*32 + quad*8);
        acc[0][nt]=mfma16(a0,bfr,acc[0][nt]);
        acc[1][nt]=mfma16(a1,bfr,acc[1][nt]);
      }
    }
  }
  #pragma unroll
  for (int Mt=0;Mt<2;Mt++)
    #pragma unroll
    for (int nt=0;nt<2;nt++)
      #pragma unroll
      for (int r=0;r<4;r++)
        partial[(long)(seq0+Mt*16+quad*4+r)*256 + (w*2+nt)*16+c] = acc[Mt][nt][r];
}

// ---------------------------------------------------------------------------
// Per-episode gate: chunks {mem, ct*mem, |ct-mem|} + partial -> g.
// ---------------------------------------------------------------------------
__global__ __launch_bounds__(512, 1) void k_gate(
    const u16* enc_hi, const u16* enc_lo, const float* mem_f,
    const float* partial, const u16* W1, const float* W2, const float* b2v, float* g)
{
  __shared__ float ctf[32][257];
  __shared__ float mvf[32][257];
  __shared__ u16 ab[32][264];
  __shared__ float pl[32][8];
  int bid=blockIdx.x, tid=threadIdx.x, seq0=bid*32;
  #pragma unroll
  for (int p=0;p<16;p++){
    int i=p*512+tid; int row=i>>8, j=i&255;
    int grow=seq0+row; int b=grow/NSENT;
    ctf[row][j]=b2f(enc_hi[(long)grow*256+j])+b2f(enc_lo[(long)grow*256+j]);
    mvf[row][j]=mem_f[b*256+j];
  }
  const int w=tid>>6, lane=tid&63, c=lane&15, quad=lane>>4;
  f32x4 acc[2][2];
  float w2v[2];
  #pragma unroll
  for (int nt=0;nt<2;nt++){
    int n=(w*2+nt)*16+c;
    w2v[nt]=W2[n];
    #pragma unroll
    for (int Mt=0;Mt<2;Mt++)
      #pragma unroll
      for (int r=0;r<4;r++)
        acc[Mt][nt][r]=partial[(long)(seq0+Mt*16+quad*4+r)*256 + n];
  }
  const int chl[3]={1,4,6};
  for (int ci=0; ci<3; ci++){
    int ch=chl[ci];
    __syncthreads();
    #pragma unroll
    for (int p=0;p<16;p++){
      int i=p*512+tid; int row=i>>8, j=i&255;
      float ct=ctf[row][j], mv=mvf[row][j];
      float v;
      if      (ch==1) v=mv;
      else if (ch==4) v=ct*mv;
      else            v=fabsf(ct-mv);
      ab[row][j]=f2b(v);
    }
    __syncthreads();
    #pragma unroll
    for (int Kt=0;Kt<8;Kt++){
      bf16x8 a0=*(const bf16x8*)&ab[c][Kt*32+quad*8];
      bf16x8 a1=*(const bf16x8*)&ab[16+c][Kt*32+quad*8];
      #pragma unroll
      for (int nt=0;nt<2;nt++){
        int n=(w*2+nt)*16+c;
        bf16x8 bfr=*(const bf16x8*)(W1 + (long)n*1792 + ch*256 + Kt*32 + quad*8);
        acc[0][nt]=mfma16(a0,bfr,acc[0][nt]);
        acc[1][nt]=mfma16(a1,bfr,acc[1][nt]);
      }
    }
  }
  float pm[8];
  #pragma unroll
  for (int i=0;i<8;i++){
    int Mt=i>>2, r=i&3;
    float s=0.f;
    #pragma unroll
    for (int nt=0;nt<2;nt++) s += tanh_(acc[Mt][nt][r])*w2v[nt];
    pm[i]=s;
  }
  #pragma unroll
  for (int off=1;off<16;off<<=1)
    #pragma unroll
    for (int i=0;i<8;i++) pm[i]+=__shfl_xor(pm[i],off,64);
  if (c==0){
    #pragma unroll
    for (int i=0;i<8;i++){ int m=(i>>2)*16+quad*4+(i&3); pl[m][w]=pm[i]; }
  }
  __syncthreads();
  if (tid<32){
    float s=b2v[0];
    #pragma unroll
    for (int ww=0;ww<8;ww++) s+=pl[tid][ww];
    g[seq0+tid]=sigm(s);
  }
}

// ---------------------------------------------------------------------------
// Episodic scan (round-2 proven structure: 4 WGs x 16 batch rows, breg[48],
// double-buffered gi_attn prefetch). Same register-budget control as
// k_enc_scan: waves_per_eu(2,2) + >80KB LDS pad.
// ---------------------------------------------------------------------------
__global__ __launch_bounds__(512) __attribute__((amdgpu_waves_per_eu(2,2)))
void k_scan(
    const u16* tWhhP, const float* tBhh,
    const float* gi_attn, const float* g,
    float* mem_f, const u16* mWihP, const u16* mWhhP,
    const float* mBih, const float* mBhh, int never)
{
  __shared__ u16 hb[16][264];
  __shared__ u16 mhi[16][264];
  __shared__ u16 mlo[16][264];
  __shared__ float memfl[16][256];
  __shared__ float gl[16][40];
  __shared__ float ldspad[10240];   // total LDS ~84.3KB -> max 1 WG/CU
  int bid=blockIdx.x, tid=threadIdx.x, b0=bid*16;
  if (never) ((volatile float*)ldspad)[tid] = 1.0f;
  const int w=tid>>6, lane=tid&63, c=lane&15, quad=lane>>4;
  for (int i=tid;i<16*264;i+=512){ ((u16*)hb)[i]=0; }
  for (int i=tid;i<4096;i+=512){
    int m=i>>8, j=i&255;
    float v=mem_f[(b0+m)*256+j]; memfl[m][j]=v;
    u16 hi_=f2b(v); mhi[m][j]=hi_; mlo[m][j]=f2b(v-b2f(hi_));
  }
  for (int i=tid;i<640;i+=512){ int m=i/40, s=i-m*40; gl[m][s]=g[(b0+m)*40+s]; }
  float biasv[6];
  #pragma unroll
  for (int nt=0;nt<6;nt++) biasv[nt]=tBhh[w*96+nt*16+c];
  uint4 breg[48];
  #pragma unroll
  for (int nt=0;nt<6;nt++)
    #pragma unroll
    for (int Kt=0;Kt<8;Kt++)
      breg[nt*8+Kt] = *(const uint4*)(tWhhP + (w*96+nt*16+c)*256 + Kt*32 + quad*8);
  float hreg[8];
  #pragma unroll
  for (int i=0;i<8;i++) hreg[i]=0.f;
  const float* gp = gi_attn + ((long)bid*NSENT)*TP + (w*64+lane)*SLOT;
  float4 pA[6];
  #pragma unroll
  for (int d=0;d<6;d++) pA[d]=*(const float4*)(gp+4*d);
  __syncthreads();

  for (int s=0;s<NSENT;s++){
    float4 pB[6];
    bool pf=(s+1<NSENT);
    if (pf){
      const float* gn = gp + (long)(s+1)*TP;
      #pragma unroll
      for (int d=0;d<6;d++) pB[d]=*(const float4*)(gn+4*d);
    }
    f32x4 acc[6];
    #pragma unroll
    for (int nt=0;nt<6;nt++) acc[nt]=(f32x4){0.f,0.f,0.f,0.f};
    #pragma unroll
    for (int Kt=0;Kt<8;Kt++){
      bf16x8 a=*(const bf16x8*)&hb[c][Kt*32+quad*8];
      #pragma unroll
      for (int nt=0;nt<6;nt++) acc[nt]=mfma16(a,*(const bf16x8*)&breg[nt*8+Kt],acc[nt]);
    }
    const float* pf32 = (const float*)&pA[0];
    #pragma unroll
    for (int r=0;r<4;r++){
      int m=quad*4+r;
      float gv = gl[m][s];
      #pragma unroll
      for (int jj=0;jj<2;jj++){
        int j=w*32+jj*16+c;
        int ib=(r*2+jj)*3;
        float ir=pf32[ib], iz=pf32[ib+1], in_=pf32[ib+2];
        float hr=acc[jj*3+0][r]+biasv[jj*3+0];
        float hz=acc[jj*3+1][r]+biasv[jj*3+1];
        float hn=acc[jj*3+2][r]+biasv[jj*3+2];
        float rr=sigm(ir+hr), zz=sigm(iz+hz), nn=tanh_(in_+rr*hn);
        float ho=hreg[r*2+jj];
        float hc=(1.f-zz)*nn+zz*ho;
        float hnew=gv*hc+(1.f-gv)*ho;
        hreg[r*2+jj]=hnew;
        hb[m][j]=f2b(hnew);
      }
    }
    __syncthreads();
    #pragma unroll
    for (int d=0;d<6;d++) pA[d]=pB[d];
  }
  // memory GRU, pi layout: ai = e@mWih'^T, ah = mem(hi+lo)@mWhh'^T
  f32x4 ai[6], ah[6];
  #pragma unroll
  for (int nt=0;nt<6;nt++){ ai[nt]=(f32x4){0.f,0.f,0.f,0.f}; ah[nt]=ai[nt]; }
  #pragma unroll
  for (int Kt=0;Kt<8;Kt++){
    bf16x8 a=*(const bf16x8*)&hb[c][Kt*32+quad*8];
    #pragma unroll
    for (int nt=0;nt<6;nt++){
      bf16x8 bfr=*(const bf16x8*)(mWihP + (w*96+nt*16+c)*256 + Kt*32 + quad*8);
      ai[nt]=mfma16(a,bfr,ai[nt]);
    }
  }
  #pragma unroll
  for (int Kt=0;Kt<8;Kt++){
    bf16x8 a=*(const bf16x8*)&mhi[c][Kt*32+quad*8];
    #pragma unroll
    for (int nt=0;nt<6;nt++){
      bf16x8 bfr=*(const bf16x8*)(mWhhP + (w*96+nt*16+c)*256 + Kt*32 + quad*8);
      ah[nt]=mfma16(a,bfr,ah[nt]);
    }
  }
  #pragma unroll
  for (int Kt=0;Kt<8;Kt++){
    bf16x8 a=*(const bf16x8*)&mlo[c][Kt*32+quad*8];
    #pragma unroll
    for (int nt=0;nt<6;nt++){
      bf16x8 bfr=*(const bf16x8*)(mWhhP + (w*96+nt*16+c)*256 + Kt*32 + quad*8);
      ah[nt]=mfma16(a,bfr,ah[nt]);
    }
  }
  float bih6[6], bhh6[6];
  #pragma unroll
  for (int nt=0;nt<6;nt++){ bih6[nt]=mBih[w*96+nt*16+c]; bhh6[nt]=mBhh[w*96+nt*16+c]; }
  #pragma unroll
  for (int r=0;r<4;r++){
    int m=quad*4+r;
    #pragma unroll
    for (int jj=0;jj<2;jj++){
      int j=w*32+jj*16+c;
      float ir=ai[jj*3+0][r]+bih6[jj*3+0];
      float iz=ai[jj*3+1][r]+bih6[jj*3+1];
      float in_=ai[jj*3+2][r]+bih6[jj*3+2];
      float hr=ah[jj*3+0][r]+bhh6[jj*3+0];
      float hz=ah[jj*3+1][r]+bhh6[jj*3+1];
      float hn=ah[jj*3+2][r]+bhh6[jj*3+2];
      float rr=sigm(ir+hr), zz=sigm(iz+hz), nn=tanh_(in_+rr*hn);
      float mo=memfl[m][j];
      mem_f[(b0+m)*256+j]=(1.f-zz)*nn+zz*mo;
    }
  }
}

// ---------------------------------------------------------------------------
// Final head, all fp32.
// ---------------------------------------------------------------------------
__global__ void k_final(const float* mem_f, const float* a1f, const float* a2f,
    const float* W1o, const float* b1o, const float* W2o, const float* b2o, float* outp)
{
  __shared__ float af[768];
  __shared__ float tl[256];
  __shared__ float lg[2];
  int b=blockIdx.x, tid=threadIdx.x;
  af[tid]     = mem_f[b*256+tid];
  af[256+tid] = a1f[b*256+tid];
  af[512+tid] = a2f[b*256+tid];
  __syncthreads();
  float s=b1o[tid];
  const float* wr=W1o + (long)tid*768;
  for (int k=0;k<768;k++) s += af[k]*wr[k];
  tl[tid]=tanh_(s);
  __syncthreads();
  if (tid<2){
    float l=b2o[tid];
    const float* w2=W2o + tid*256;
    for (int k=0;k<256;k++) l += tl[k]*w2[k];
    lg[tid]=l;
  }
  __syncthreads();
  if (tid==0){
    float m=fmaxf(lg[0],lg[1]);
    float e0=__expf(lg[0]-m), e1=__expf(lg[1]-m);
    float inv=1.f/(e0+e1);
    outp[b*2]=e0*inv; outp[b*2+1]=e1*inv;
  }
}

// ---------------------------------------------------------------------------
extern "C" void kernel_launch(void* const* d_in, const int* in_sizes, int n_in,
                              void* d_out, int out_size, void* d_ws, size_t ws_size,
                              hipStream_t stream) {
  const int* c_p   = (const int*)d_in[0];
  const int* c_m   = (const int*)d_in[1];
  const int* q_p   = (const int*)d_in[2];
  const int* q_m   = (const int*)d_in[3];
  const int* a1p   = (const int*)d_in[4];
  const int* a1m   = (const int*)d_in[5];
  const int* a2p   = (const int*)d_in[6];
  const int* a2m   = (const int*)d_in[7];
  const float* embed = (const float*)d_in[8];
  const float* cWih=(const float*)d_in[9],  *cWhh=(const float*)d_in[10], *cbih=(const float*)d_in[11], *cbhh=(const float*)d_in[12];
  const float* qWih=(const float*)d_in[13], *qWhh=(const float*)d_in[14], *qbih=(const float*)d_in[15], *qbhh=(const float*)d_in[16];
  const float* aWih=(const float*)d_in[17], *aWhh=(const float*)d_in[18], *abih=(const float*)d_in[19], *abhh=(const float*)d_in[20];
  const float* tWih=(const float*)d_in[21], *tWhh=(const float*)d_in[22], *tbih=(const float*)d_in[23], *tbhh=(const float*)d_in[24];
  const float* mWih=(const float*)d_in[25], *mWhh=(const float*)d_in[26], *mbih=(const float*)d_in[27], *mbhh=(const float*)d_in[28];
  const float* gW1=(const float*)d_in[29], *gb1=(const float*)d_in[30], *gW2=(const float*)d_in[31], *gb2=(const float*)d_in[32];
  const float* oW1=(const float*)d_in[33], *ob1=(const float*)d_in[34], *oW2=(const float*)d_in[35], *ob2=(const float*)d_in[36];

  char* ws = (char*)d_ws;
  size_t off = 0;
  u16* P[10];
  for (int i=0;i<10;i++){ P[i]=(u16*)(ws+off); off+=393216; }
  u16* PgW1 =(u16*)(ws+off); off+=917504;
  float* B[10];
  for (int i=0;i<10;i++){ B[i]=(float*)(ws+off); off+=3072; }
  u16* gi_c =(u16*)(ws+off); off+=(size_t)160*SLEN*TP*2;   // 118 MB
  u16* gi_q =(u16*)(ws+off); off+=(size_t)4*QLEN*TP*2;
  u16* gi_a1=(u16*)(ws+off); off+=(size_t)4*ALEN*TP*2;
  u16* gi_a2=(u16*)(ws+off); off+=(size_t)4*ALEN*TP*2;
  u16* enc_hi=(u16*)(ws+off); off+=(size_t)SCTX*256*2;
  u16* enc_lo=(u16*)(ws+off); off+=(size_t)SCTX*256*2;
  float* enc_qf =(float*)(ws+off); off+=64*256*4;
  float* enc_a1f=(float*)(ws+off); off+=64*256*4;
  float* enc_a2f=(float*)(ws+off); off+=64*256*4;
  float* mem_f  =(float*)(ws+off); off+=64*256*4;
  float* gi_attn=(float*)(ws+off); off+=(size_t)160*TP*4;  // 7.9 MB
  float* partial=(float*)(ws+off); off+=(size_t)SCTX*256*4;
  float* gbuf   =(float*)(ws+off); off+=SCTX*4;

  k_prep<<<4751, 512, 0, stream>>>(cWih,cWhh,qWih,qWhh,aWih,aWhh,tWih,tWhh,mWih,mWhh,gW1,
      cbih,cbhh,qbih,qbhh,abih,abhh,tbih,tbhh,mbih,mbhh,
      P[0],P[1],P[2],P[3],P[4],P[5],P[6],P[7],P[8],P[9], PgW1,
      B[0],B[1],B[2],B[3],B[4],B[5],B[6],B[7],B[8],B[9]);

  k_xproj<<<1244, 512, 0, stream>>>(c_p,q_p,a1p,a2p, embed,
      P[0],P[2],P[4], B[0],B[2],B[4], gi_c,gi_q,gi_a1,gi_a2);

  k_enc_scan<<<172, 512, 0, stream>>>(c_m,q_m,a1m,a2m,
      P[1],P[3],P[5], B[1],B[3],B[5], gi_c,gi_q,gi_a1,gi_a2,
      enc_hi,enc_lo, enc_qf,enc_a1f,enc_a2f, 0);

  k_gi<<<161, 512, 0, stream>>>(enc_hi,enc_lo, P[6], B[6], gi_attn, enc_qf, mem_f);

  k_gatepre<<<80, 512, 0, stream>>>(enc_hi,enc_lo, enc_qf, PgW1, gb1, partial);

  for (int ep=0; ep<3; ep++){
    k_gate<<<80, 512, 0, stream>>>(enc_hi,enc_lo, mem_f, partial, PgW1, gW2, gb2, gbuf);
    k_scan<<<4, 512, 0, stream>>>(P[7], B[7], gi_attn, gbuf, mem_f, P[8], P[9], B[8], B[9], 0);
  }

  k_final<<<64, 256, 0, stream>>>(mem_f, enc_a1f, enc_a2f, oW1, ob1, oW2, ob2, (float*)d_out);
}

// Round 8
// 894.392 us; speedup vs baseline: 1.4218x; 1.0423x over previous
//
#include <hip/hip_runtime.h>

typedef unsigned short u16;
typedef __bf16 bf16x8 __attribute__((ext_vector_type(8)));
typedef float f32x4 __attribute__((ext_vector_type(4)));
typedef float f32x4v __attribute__((ext_vector_type(4)));
typedef unsigned int u32x2 __attribute__((ext_vector_type(2)));

#define NSENT 40
#define SLEN 30
#define QLEN 20
#define ALEN 12
#define SCTX 2560
#define SLOT 24              // u16 (or fp32) values per lane-slot
#define TP 12288             // 512*24 elements per (block,t) plane

__device__ __forceinline__ float b2f(u16 u){ union{float f; unsigned i;} v; v.i = ((unsigned)u)<<16; return v.f; }
__device__ __forceinline__ u16 f2b(float f){ union{float f; unsigned u;} v; v.f=f; unsigned u=v.u; u += ((u>>16)&1u) + 0x7fffu; return (u16)(u>>16); }
__device__ __forceinline__ float sigm(float x){ return __builtin_amdgcn_rcpf(1.f + __expf(-x)); }
__device__ __forceinline__ float tanh_(float x){
  float a = fminf(fmaxf(2.f*x, -30.f), 30.f);
  float e = __expf(a);
  return 1.f - 2.f*__builtin_amdgcn_rcpf(e + 1.f);
}
__device__ __forceinline__ f32x4 mfma16(bf16x8 a, bf16x8 b, f32x4 c){
  return __builtin_amdgcn_mfma_f32_16x16x32_bf16(a, b, c, 0, 0, 0);
}

// ---------------------------------------------------------------------------
// Prep: pi-permute (n' = g16*48 + gate*16 + c <-> j = gate*256 + g16*16 + c)
// 10 weight mats -> bf16 P0..P9; gW1 plain bf16; 10 pi-permuted fp32 biases.
// ---------------------------------------------------------------------------
__global__ void k_prep(
    const float* cWih, const float* cWhh, const float* qWih, const float* qWhh,
    const float* aWih, const float* aWhh, const float* tWih, const float* tWhh,
    const float* mWih, const float* mWhh, const float* gW1,
    const float* cbih, const float* cbhh, const float* qbih, const float* qbhh,
    const float* abih, const float* abhh, const float* tbih, const float* tbhh,
    const float* mbih, const float* mbhh,
    u16* P0,u16* P1,u16* P2,u16* P3,u16* P4,u16* P5,u16* P6,u16* P7,u16* P8,u16* P9,
    u16* PgW1,
    float* B0,float* B1,float* B2,float* B3,float* B4,float* B5,float* B6,float* B7,
    float* B8,float* B9)
{
  int i = blockIdx.x*512 + threadIdx.x;   // 4751*512 = 2,432,512
  if (i < 1966080){
    int seg = i/196608; int e = i - seg*196608;
    int np = e>>8, k = e&255;
    int g16 = np/48, rem = np - g16*48, gate = rem>>4, cc = rem&15;
    int j = gate*256 + g16*16 + cc;
    const float* S; u16* D;
    switch(seg){
      case 0: S=cWih; D=P0; break; case 1: S=cWhh; D=P1; break;
      case 2: S=qWih; D=P2; break; case 3: S=qWhh; D=P3; break;
      case 4: S=aWih; D=P4; break; case 5: S=aWhh; D=P5; break;
      case 6: S=tWih; D=P6; break; case 7: S=tWhh; D=P7; break;
      case 8: S=mWih; D=P8; break; default: S=mWhh; D=P9; break;
    }
    D[e] = f2b(S[j*256 + k]);
  } else if (i < 2424832){
    int e = i - 1966080;
    PgW1[e] = f2b(gW1[e]);
  } else {
    int e = i - 2424832;                  // 7680 = 10*768
    int seg = e/768; int np = e - seg*768;
    int g16 = np/48, rem = np - g16*48, gate = rem>>4, cc = rem&15;
    int j = gate*256 + g16*16 + cc;
    const float* S; float* D;
    switch(seg){
      case 0: S=cbih; D=B0; break; case 1: S=cbhh; D=B1; break;
      case 2: S=qbih; D=B2; break; case 3: S=qbhh; D=B3; break;
      case 4: S=abih; D=B4; break; case 5: S=abhh; D=B5; break;
      case 6: S=tbih; D=B6; break; case 7: S=tbhh; D=B7; break;
      case 8: S=mbih; D=B8; break; default: S=mbhh; D=B9; break;
    }
    D[np] = S[j];
  }
}

// ---------------------------------------------------------------------------
// x-projections. 64 rows/block (32 seqs x 2 t); nt embed loads + nt gi stores
// keep the 393KB weight matrix L2-resident.
// gi plane layout: plane*TP + jj*6144 + (w8*64+lane)*12 + (r*3+g).
// ---------------------------------------------------------------------------
__global__ __launch_bounds__(512, 4) void k_xproj(
    const int* c_p, const int* q_p, const int* a1p, const int* a2p,
    const float* embed,
    const u16* cWihP, const u16* qWihP, const u16* aWihP,
    const float* cBih, const float* qBih, const float* aBih,
    u16* gi_c, u16* gi_q, u16* gi_a1, u16* gi_a2)
{
  __shared__ u16 xb[64][288];
  int bid=blockIdx.x, tid=threadIdx.x;
  const int* toks; const u16* W; const float* bias; u16* out; int T, blk32, t0;
  if (bid < 1200){ toks=c_p; W=cWihP; bias=cBih; out=gi_c; T=SLEN; blk32=bid/15; t0=(bid-blk32*15)*2; }
  else if (bid < 1220){ int e=bid-1200; toks=q_p; W=qWihP; bias=qBih; out=gi_q; T=QLEN; blk32=e/10; t0=(e-blk32*10)*2; }
  else if (bid < 1232){ int e=bid-1220; toks=a1p; W=aWihP; bias=aBih; out=gi_a1; T=ALEN; blk32=e/6; t0=(e-blk32*6)*2; }
  else               { int e=bid-1232; toks=a2p; W=aWihP; bias=aBih; out=gi_a2; T=ALEN; blk32=e/6; t0=(e-blk32*6)*2; }
  int seq0 = blk32*32;
  #pragma unroll
  for (int p=0;p<8;p++){
    int i=p*512+tid; int row=i>>6, f4=i&63;   // row wave-uniform
    int tp=row>>5, sm=row&31;
    int tok = toks[(seq0+sm)*T + t0+tp];
    f32x4v v = __builtin_nontemporal_load((const f32x4v*)(embed + (long)tok*256) + f4);
    unsigned lo = (unsigned)f2b(v[0]) | ((unsigned)f2b(v[1])<<16);
    unsigned hi = (unsigned)f2b(v[2]) | ((unsigned)f2b(v[3])<<16);
    u32x2 pk; pk.x=lo; pk.y=hi;
    *(u32x2*)&xb[row][f4*4] = pk;
  }
  const int w=tid>>6, lane=tid&63, c=lane&15, quad=lane>>4;
  __syncthreads();
  #pragma unroll
  for (int jj=0;jj<2;jj++){
    f32x4 acc[4][3];
    #pragma unroll
    for (int Mt=0;Mt<4;Mt++)
      #pragma unroll
      for (int g=0;g<3;g++) acc[Mt][g]=(f32x4){0.f,0.f,0.f,0.f};
    #pragma unroll
    for (int Kt=0;Kt<8;Kt++){
      bf16x8 a0=*(const bf16x8*)&xb[c][Kt*32+quad*8];
      bf16x8 a1=*(const bf16x8*)&xb[16+c][Kt*32+quad*8];
      bf16x8 a2=*(const bf16x8*)&xb[32+c][Kt*32+quad*8];
      bf16x8 a3=*(const bf16x8*)&xb[48+c][Kt*32+quad*8];
      #pragma unroll
      for (int g=0;g<3;g++){
        bf16x8 bfr=*(const bf16x8*)(W + (w*96+(jj*3+g)*16+c)*256 + Kt*32 + quad*8);
        acc[0][g]=mfma16(a0,bfr,acc[0][g]);
        acc[1][g]=mfma16(a1,bfr,acc[1][g]);
        acc[2][g]=mfma16(a2,bfr,acc[2][g]);
        acc[3][g]=mfma16(a3,bfr,acc[3][g]);
      }
    }
    float bv[3];
    #pragma unroll
    for (int g=0;g<3;g++) bv[g]=bias[w*96+(jj*3+g)*16+c];
    #pragma unroll
    for (int Mt=0;Mt<4;Mt++){
      int tp=Mt>>1, smh=Mt&1;
      unsigned d[6];
      #pragma unroll
      for (int k=0;k<6;k++){
        int s0=2*k, s1=2*k+1;
        int r0=s0/3, g0=s0%3, r1=s1/3, g1=s1%3;
        unsigned lo=f2b(acc[Mt][g0][r0]+bv[g0]);
        unsigned hi=f2b(acc[Mt][g1][r1]+bv[g1]);
        d[k]=lo|(hi<<16);
      }
      long block16 = (long)blk32*2 + smh;
      u16* dst = out + (block16*T + t0+tp)*TP + jj*6144 + (w*64+lane)*12;
      u32x2 s0v; s0v.x=d[0]; s0v.y=d[1];
      u32x2 s1v; s1v.x=d[2]; s1v.y=d[3];
      u32x2 s2v; s2v.x=d[4]; s2v.y=d[5];
      __builtin_nontemporal_store(s0v, (u32x2*)dst);
      __builtin_nontemporal_store(s1v, (u32x2*)(dst+4));
      __builtin_nontemporal_store(s2v, (u32x2*)(dst+8));
    }
  }
}

// ---------------------------------------------------------------------------
// Recurrent encoder scans: packed gi via 6 per-lane u32x2 loads (jj-grouped
// layout), prefetch-1, no gi LDS. 172 WGs x 16 seqs, 1 barrier/step.
// (Round-2 proven structure; VGPR cap 128, compiler remats breg overflow
// from L2 — measured 136us. Rounds 3/5/6/7 restructures all regressed.)
// ---------------------------------------------------------------------------
__global__ __launch_bounds__(512, 2) void k_enc_scan(
    const int* c_mask, const int* q_mask, const int* a1m, const int* a2m,
    const u16* cWhhP, const u16* qWhhP, const u16* aWhhP,
    const float* cBhh, const float* qBhh, const float* aBhh,
    const u16* gi_c, const u16* gi_q, const u16* gi_a1, const u16* gi_a2,
    u16* enc_hi, u16* enc_lo, float* enc_qf, float* enc_a1f, float* enc_a2f)
{
  __shared__ u16 hhi[16][264];
  __shared__ u16 hlo[16][264];
  __shared__ int idxs[16];
  int bid=blockIdx.x, tid=threadIdx.x;
  const int* msk; const u16* W; const float* bhh; const u16* gi; int T, seq0, mode;
  u16 *ohi=0, *olo=0; float* of=0;
  if (bid<160){ msk=c_mask; W=cWhhP; bhh=cBhh; gi=gi_c+(long)bid*SLEN*TP; T=SLEN; seq0=bid*16; mode=0; ohi=enc_hi; olo=enc_lo; }
  else if (bid<164){ int e=bid-160; msk=q_mask; W=qWhhP; bhh=qBhh; gi=gi_q+(long)e*QLEN*TP; T=QLEN; seq0=e*16; mode=1; of=enc_qf; }
  else if (bid<168){ int e=bid-164; msk=a1m; W=aWhhP; bhh=aBhh; gi=gi_a1+(long)e*ALEN*TP; T=ALEN; seq0=e*16; mode=1; of=enc_a1f; }
  else             { int e=bid-168; msk=a2m; W=aWhhP; bhh=aBhh; gi=gi_a2+(long)e*ALEN*TP; T=ALEN; seq0=e*16; mode=1; of=enc_a2f; }
  if (tid<16){
    int len=0; const int* mr=msk+(seq0+tid)*T;
    for (int t=0;t<T;t++) len += (mr[t]==0);
    int id=len-1; if(id<0)id=0; if(id>T-1)id=T-1; idxs[tid]=id;
  }
  for (int i=tid;i<16*264;i+=512){ ((u16*)hhi)[i]=0; ((u16*)hlo)[i]=0; }
  const int w=tid>>6, lane=tid&63, c=lane&15, quad=lane>>4;
  float biasv[6];
  #pragma unroll
  for (int nt=0;nt<6;nt++) biasv[nt]=bhh[w*96+nt*16+c];
  uint4 breg[48];
  #pragma unroll
  for (int nt=0;nt<6;nt++)
    #pragma unroll
    for (int Kt=0;Kt<8;Kt++)
      breg[nt*8+Kt] = *(const uint4*)(W + (w*96+nt*16+c)*256 + Kt*32 + quad*8);
  float hreg[8];
  #pragma unroll
  for (int i=0;i<8;i++) hreg[i]=0.f;
  const u16* gp = gi + (w*64+lane)*12;
  u32x2 pA0=*(const u32x2*)(gp),      pA1=*(const u32x2*)(gp+4),    pA2=*(const u32x2*)(gp+8);
  u32x2 pA3=*(const u32x2*)(gp+6144), pA4=*(const u32x2*)(gp+6148), pA5=*(const u32x2*)(gp+6152);
  __syncthreads();
  int idxr[4];
  #pragma unroll
  for (int r=0;r<4;r++) idxr[r]=idxs[quad*4+r];

  for (int t=0;t<T;t++){
    u32x2 pB0,pB1,pB2,pB3,pB4,pB5;
    bool pf=(t+1<T);
    if (pf){
      const u16* gn = gp + (long)(t+1)*TP;
      pB0=*(const u32x2*)(gn);      pB1=*(const u32x2*)(gn+4);    pB2=*(const u32x2*)(gn+8);
      pB3=*(const u32x2*)(gn+6144); pB4=*(const u32x2*)(gn+6148); pB5=*(const u32x2*)(gn+6152);
    }
    f32x4 acc[6];
    #pragma unroll
    for (int nt=0;nt<6;nt++) acc[nt]=(f32x4){0.f,0.f,0.f,0.f};
    #pragma unroll
    for (int Kt=0;Kt<8;Kt++){
      bf16x8 a=*(const bf16x8*)&hhi[c][Kt*32+quad*8];
      #pragma unroll
      for (int nt=0;nt<6;nt++) acc[nt]=mfma16(a,*(const bf16x8*)&breg[nt*8+Kt],acc[nt]);
    }
    #pragma unroll
    for (int Kt=0;Kt<8;Kt++){
      bf16x8 a=*(const bf16x8*)&hlo[c][Kt*32+quad*8];
      #pragma unroll
      for (int nt=0;nt<6;nt++) acc[nt]=mfma16(a,*(const bf16x8*)&breg[nt*8+Kt],acc[nt]);
    }
    unsigned pd[12];
    *(u32x2*)&pd[0]=pA0; *(u32x2*)&pd[2]=pA1; *(u32x2*)&pd[4]=pA2;
    *(u32x2*)&pd[6]=pA3; *(u32x2*)&pd[8]=pA4; *(u32x2*)&pd[10]=pA5;
    #pragma unroll
    for (int r=0;r<4;r++){
      int m=quad*4+r;
      #pragma unroll
      for (int jj=0;jj<2;jj++){
        int j=w*32+jj*16+c;
        int ib=r*3;   // slot within jj region; words at pd[jj*6 + ...]
        float ir = b2f((u16)((pd[jj*6+(ib>>1)]     >> ((ib&1)*16)) & 0xffffu));
        float iz = b2f((u16)((pd[jj*6+((ib+1)>>1)] >> (((ib+1)&1)*16)) & 0xffffu));
        float in_= b2f((u16)((pd[jj*6+((ib+2)>>1)] >> (((ib+2)&1)*16)) & 0xffffu));
        float hr=acc[jj*3+0][r]+biasv[jj*3+0];
        float hz=acc[jj*3+1][r]+biasv[jj*3+1];
        float hn=acc[jj*3+2][r]+biasv[jj*3+2];
        float rr=sigm(ir+hr), zz=sigm(iz+hz), nn=tanh_(in_+rr*hn);
        float ho=hreg[r*2+jj];
        float hnew=(1.f-zz)*nn+zz*ho;
        hreg[r*2+jj]=hnew;
        u16 hi_=f2b(hnew); u16 lo_=f2b(hnew-b2f(hi_));
        hhi[m][j]=hi_; hlo[m][j]=lo_;
        if (t==idxr[r]){
          long o=(long)(seq0+m)*256+j;
          if (mode==0){ ohi[o]=hi_; olo[o]=lo_; }
          else of[o]=hnew;
        }
      }
    }
    __syncthreads();
    pA0=pB0; pA1=pB1; pA2=pB2; pA3=pB3; pA4=pB4; pA5=pB5;
  }
}

// ---------------------------------------------------------------------------
// gi_attn packed fp32: WG = (b-block of 16, sentence s). 160 WGs + init WG.
// Slot: gi_attn[(bblk*40+s)*TP + (w*64+lane)*24 + (r*2+jj)*3+gate]
// ---------------------------------------------------------------------------
__global__ __launch_bounds__(512, 2) void k_gi(
    const u16* enc_hi, const u16* enc_lo, const u16* tWihP, const float* tBih,
    float* gi_attn, const float* enc_qf, float* mem_f)
{
  int bid=blockIdx.x, tid=threadIdx.x;
  if (bid==160){ for (int i=tid;i<64*256;i+=512) mem_f[i]=enc_qf[i]; return; }
  __shared__ u16 ahi[16][264];
  __shared__ u16 alo[16][264];
  int bblk=bid/40, s=bid-bblk*40, b0=bblk*16;
  {
    int row=tid>>5, ch=tid&31;
    long seq=(long)(b0+row)*NSENT + s;
    *(uint4*)((char*)&ahi[row][0]+ch*16) = *((const uint4*)(enc_hi+seq*256)+ch);
    *(uint4*)((char*)&alo[row][0]+ch*16) = *((const uint4*)(enc_lo+seq*256)+ch);
  }
  const int w=tid>>6, lane=tid&63, c=lane&15, quad=lane>>4;
  f32x4 acc[6];
  #pragma unroll
  for (int nt=0;nt<6;nt++) acc[nt]=(f32x4){0.f,0.f,0.f,0.f};
  __syncthreads();
  #pragma unroll
  for (int Kt=0;Kt<8;Kt++){
    bf16x8 a=*(const bf16x8*)&ahi[c][Kt*32+quad*8];
    #pragma unroll
    for (int nt=0;nt<6;nt++){
      bf16x8 bfr=*(const bf16x8*)(tWihP + (w*96+nt*16+c)*256 + Kt*32 + quad*8);
      acc[nt]=mfma16(a,bfr,acc[nt]);
    }
  }
  #pragma unroll
  for (int Kt=0;Kt<8;Kt++){
    bf16x8 a=*(const bf16x8*)&alo[c][Kt*32+quad*8];
    #pragma unroll
    for (int nt=0;nt<6;nt++){
      bf16x8 bfr=*(const bf16x8*)(tWihP + (w*96+nt*16+c)*256 + Kt*32 + quad*8);
      acc[nt]=mfma16(a,bfr,acc[nt]);
    }
  }
  float biasv[6];
  #pragma unroll
  for (int nt=0;nt<6;nt++) biasv[nt]=tBih[w*96+nt*16+c];
  float* dst = gi_attn + ((long)(bblk*40+s))*TP + (w*64+lane)*SLOT;
  #pragma unroll
  for (int d=0;d<6;d++){
    float4 v;
    #pragma unroll
    for (int e=0;e<4;e++){
      int idx=4*d+e;
      int r=idx/6, rem=idx%6, jj=rem/3, g=rem%3;
      ((float*)&v)[e]=acc[jj*3+g][r]+biasv[jj*3+g];
    }
    *(float4*)(dst+4*d)=v;
  }
}

// ---------------------------------------------------------------------------
// Gate precompute (episode-invariant chunks {ct,q,ct*q,|ct-q|}).
// ---------------------------------------------------------------------------
__global__ __launch_bounds__(512, 1) void k_gatepre(
    const u16* enc_hi, const u16* enc_lo, const float* enc_qf,
    const u16* W1, const float* b1, float* partial)
{
  __shared__ float ctf[32][257];
  __shared__ float qvf[32][257];
  __shared__ u16 ab[32][264];
  int bid=blockIdx.x, tid=threadIdx.x, seq0=bid*32;
  #pragma unroll
  for (int p=0;p<16;p++){
    int i=p*512+tid; int row=i>>8, j=i&255;
    int grow=seq0+row; int b=grow/NSENT;
    ctf[row][j]=b2f(enc_hi[(long)grow*256+j])+b2f(enc_lo[(long)grow*256+j]);
    qvf[row][j]=enc_qf[b*256+j];
  }
  const int w=tid>>6, lane=tid&63, c=lane&15, quad=lane>>4;
  f32x4 acc[2][2];
  #pragma unroll
  for (int nt=0;nt<2;nt++){
    float bv=b1[(w*2+nt)*16+c];
    acc[0][nt]=(f32x4){bv,bv,bv,bv}; acc[1][nt]=acc[0][nt];
  }
  const int chl[4]={0,2,3,5};
  for (int ci=0; ci<4; ci++){
    int ch=chl[ci];
    __syncthreads();
    #pragma unroll
    for (int p=0;p<16;p++){
      int i=p*512+tid; int row=i>>8, j=i&255;
      float ct=ctf[row][j], qv=qvf[row][j];
      float v;
      if      (ch==0) v=ct;
      else if (ch==2) v=qv;
      else if (ch==3) v=ct*qv;
      else            v=fabsf(ct-qv);
      ab[row][j]=f2b(v);
    }
    __syncthreads();
    #pragma unroll
    for (int Kt=0;Kt<8;Kt++){
      bf16x8 a0=*(const bf16x8*)&ab[c][Kt*32+quad*8];
      bf16x8 a1=*(const bf16x8*)&ab[16+c][Kt*32+quad*8];
      #pragma unroll
      for (int nt=0;nt<2;nt++){
        int n=(w*2+nt)*16+c;
        bf16x8 bfr=*(const bf16x8*)(W1 + (long)n*1792 + ch*256 + Kt*32 + quad*8);
        acc[0][nt]=mfma16(a0,bfr,acc[0][nt]);
        acc[1][nt]=mfma16(a1,bfr,acc[1][nt]);
      }
    }
  }
  #pragma unroll
  for (int Mt=0;Mt<2;Mt++)
    #pragma unroll
    for (int nt=0;nt<2;nt++)
      #pragma unroll
      for (int r=0;r<4;r++)
        partial[(long)(seq0+Mt*16+quad*4+r)*256 + (w*2+nt)*16+c] = acc[Mt][nt][r];
}

// ---------------------------------------------------------------------------
// Per-episode gate: chunks {mem, ct*mem, |ct-mem|} + partial -> g.
// ---------------------------------------------------------------------------
__global__ __launch_bounds__(512, 1) void k_gate(
    const u16* enc_hi, const u16* enc_lo, const float* mem_f,
    const float* partial, const u16* W1, const float* W2, const float* b2v, float* g)
{
  __shared__ float ctf[32][257];
  __shared__ float mvf[32][257];
  __shared__ u16 ab[32][264];
  __shared__ float pl[32][8];
  int bid=blockIdx.x, tid=threadIdx.x, seq0=bid*32;
  #pragma unroll
  for (int p=0;p<16;p++){
    int i=p*512+tid; int row=i>>8, j=i&255;
    int grow=seq0+row; int b=grow/NSENT;
    ctf[row][j]=b2f(enc_hi[(long)grow*256+j])+b2f(enc_lo[(long)grow*256+j]);
    mvf[row][j]=mem_f[b*256+j];
  }
  const int w=tid>>6, lane=tid&63, c=lane&15, quad=lane>>4;
  f32x4 acc[2][2];
  float w2v[2];
  #pragma unroll
  for (int nt=0;nt<2;nt++){
    int n=(w*2+nt)*16+c;
    w2v[nt]=W2[n];
    #pragma unroll
    for (int Mt=0;Mt<2;Mt++)
      #pragma unroll
      for (int r=0;r<4;r++)
        acc[Mt][nt][r]=partial[(long)(seq0+Mt*16+quad*4+r)*256 + n];
  }
  const int chl[3]={1,4,6};
  for (int ci=0; ci<3; ci++){
    int ch=chl[ci];
    __syncthreads();
    #pragma unroll
    for (int p=0;p<16;p++){
      int i=p*512+tid; int row=i>>8, j=i&255;
      float ct=ctf[row][j], mv=mvf[row][j];
      float v;
      if      (ch==1) v=mv;
      else if (ch==4) v=ct*mv;
      else            v=fabsf(ct-mv);
      ab[row][j]=f2b(v);
    }
    __syncthreads();
    #pragma unroll
    for (int Kt=0;Kt<8;Kt++){
      bf16x8 a0=*(const bf16x8*)&ab[c][Kt*32+quad*8];
      bf16x8 a1=*(const bf16x8*)&ab[16+c][Kt*32+quad*8];
      #pragma unroll
      for (int nt=0;nt<2;nt++){
        int n=(w*2+nt)*16+c;
        bf16x8 bfr=*(const bf16x8*)(W1 + (long)n*1792 + ch*256 + Kt*32 + quad*8);
        acc[0][nt]=mfma16(a0,bfr,acc[0][nt]);
        acc[1][nt]=mfma16(a1,bfr,acc[1][nt]);
      }
    }
  }
  float pm[8];
  #pragma unroll
  for (int i=0;i<8;i++){
    int Mt=i>>2, r=i&3;
    float s=0.f;
    #pragma unroll
    for (int nt=0;nt<2;nt++) s += tanh_(acc[Mt][nt][r])*w2v[nt];
    pm[i]=s;
  }
  #pragma unroll
  for (int off=1;off<16;off<<=1)
    #pragma unroll
    for (int i=0;i<8;i++) pm[i]+=__shfl_xor(pm[i],off,64);
  if (c==0){
    #pragma unroll
    for (int i=0;i<8;i++){ int m=(i>>2)*16+quad*4+(i&3); pl[m][w]=pm[i]; }
  }
  __syncthreads();
  if (tid<32){
    float s=b2v[0];
    #pragma unroll
    for (int ww=0;ww<8;ww++) s+=pl[tid][ww];
    g[seq0+tid]=sigm(s);
  }
}

// ---------------------------------------------------------------------------
// Episodic scan: 4 WGs x 16 batch rows; attn_Whh' VGPR-resident; packed
// gi_attn prefetch; all-lane elementwise; pi mem-GRU tail (lane-local).
// ---------------------------------------------------------------------------
__global__ __launch_bounds__(512, 2) void k_scan(
    const u16* tWhhP, const float* tBhh,
    const float* gi_attn, const float* g,
    float* mem_f, const u16* mWihP, const u16* mWhhP,
    const float* mBih, const float* mBhh)
{
  __shared__ u16 hb[16][264];
  __shared__ u16 mhi[16][264];
  __shared__ u16 mlo[16][264];
  __shared__ float memfl[16][256];
  __shared__ float gl[16][40];
  int bid=blockIdx.x, tid=threadIdx.x, b0=bid*16;
  const int w=tid>>6, lane=tid&63, c=lane&15, quad=lane>>4;
  for (int i=tid;i<16*264;i+=512){ ((u16*)hb)[i]=0; }
  for (int i=tid;i<4096;i+=512){
    int m=i>>8, j=i&255;
    float v=mem_f[(b0+m)*256+j]; memfl[m][j]=v;
    u16 hi_=f2b(v); mhi[m][j]=hi_; mlo[m][j]=f2b(v-b2f(hi_));
  }
  for (int i=tid;i<640;i+=512){ int m=i/40, s=i-m*40; gl[m][s]=g[(b0+m)*40+s]; }
  float biasv[6];
  #pragma unroll
  for (int nt=0;nt<6;nt++) biasv[nt]=tBhh[w*96+nt*16+c];
  uint4 breg[48];
  #pragma unroll
  for (int nt=0;nt<6;nt++)
    #pragma unroll
    for (int Kt=0;Kt<8;Kt++)
      breg[nt*8+Kt] = *(const uint4*)(tWhhP + (w*96+nt*16+c)*256 + Kt*32 + quad*8);
  float hreg[8];
  #pragma unroll
  for (int i=0;i<8;i++) hreg[i]=0.f;
  const float* gp = gi_attn + ((long)bid*NSENT)*TP + (w*64+lane)*SLOT;
  float4 pA[6];
  #pragma unroll
  for (int d=0;d<6;d++) pA[d]=*(const float4*)(gp+4*d);
  __syncthreads();

  for (int s=0;s<NSENT;s++){
    float4 pB[6];
    bool pf=(s+1<NSENT);
    if (pf){
      const float* gn = gp + (long)(s+1)*TP;
      #pragma unroll
      for (int d=0;d<6;d++) pB[d]=*(const float4*)(gn+4*d);
    }
    f32x4 acc[6];
    #pragma unroll
    for (int nt=0;nt<6;nt++) acc[nt]=(f32x4){0.f,0.f,0.f,0.f};
    #pragma unroll
    for (int Kt=0;Kt<8;Kt++){
      bf16x8 a=*(const bf16x8*)&hb[c][Kt*32+quad*8];
      #pragma unroll
      for (int nt=0;nt<6;nt++) acc[nt]=mfma16(a,*(const bf16x8*)&breg[nt*8+Kt],acc[nt]);
    }
    const float* pf32 = (const float*)&pA[0];
    #pragma unroll
    for (int r=0;r<4;r++){
      int m=quad*4+r;
      float gv = gl[m][s];
      #pragma unroll
      for (int jj=0;jj<2;jj++){
        int j=w*32+jj*16+c;
        int ib=(r*2+jj)*3;
        float ir=pf32[ib], iz=pf32[ib+1], in_=pf32[ib+2];
        float hr=acc[jj*3+0][r]+biasv[jj*3+0];
        float hz=acc[jj*3+1][r]+biasv[jj*3+1];
        float hn=acc[jj*3+2][r]+biasv[jj*3+2];
        float rr=sigm(ir+hr), zz=sigm(iz+hz), nn=tanh_(in_+rr*hn);
        float ho=hreg[r*2+jj];
        float hc=(1.f-zz)*nn+zz*ho;
        float hnew=gv*hc+(1.f-gv)*ho;
        hreg[r*2+jj]=hnew;
        hb[m][j]=f2b(hnew);
      }
    }
    __syncthreads();
    #pragma unroll
    for (int d=0;d<6;d++) pA[d]=pB[d];
  }
  // memory GRU, pi layout: ai = e@mWih'^T, ah = mem(hi+lo)@mWhh'^T
  f32x4 ai[6], ah[6];
  #pragma unroll
  for (int nt=0;nt<6;nt++){ ai[nt]=(f32x4){0.f,0.f,0.f,0.f}; ah[nt]=ai[nt]; }
  #pragma unroll
  for (int Kt=0;Kt<8;Kt++){
    bf16x8 a=*(const bf16x8*)&hb[c][Kt*32+quad*8];
    #pragma unroll
    for (int nt=0;nt<6;nt++){
      bf16x8 bfr=*(const bf16x8*)(mWihP + (w*96+nt*16+c)*256 + Kt*32 + quad*8);
      ai[nt]=mfma16(a,bfr,ai[nt]);
    }
  }
  #pragma unroll
  for (int Kt=0;Kt<8;Kt++){
    bf16x8 a=*(const bf16x8*)&mhi[c][Kt*32+quad*8];
    #pragma unroll
    for (int nt=0;nt<6;nt++){
      bf16x8 bfr=*(const bf16x8*)(mWhhP + (w*96+nt*16+c)*256 + Kt*32 + quad*8);
      ah[nt]=mfma16(a,bfr,ah[nt]);
    }
  }
  #pragma unroll
  for (int Kt=0;Kt<8;Kt++){
    bf16x8 a=*(const bf16x8*)&mlo[c][Kt*32+quad*8];
    #pragma unroll
    for (int nt=0;nt<6;nt++){
      bf16x8 bfr=*(const bf16x8*)(mWhhP + (w*96+nt*16+c)*256 + Kt*32 + quad*8);
      ah[nt]=mfma16(a,bfr,ah[nt]);
    }
  }
  float bih6[6], bhh6[6];
  #pragma unroll
  for (int nt=0;nt<6;nt++){ bih6[nt]=mBih[w*96+nt*16+c]; bhh6[nt]=mBhh[w*96+nt*16+c]; }
  #pragma unroll
  for (int r=0;r<4;r++){
    int m=quad*4+r;
    #pragma unroll
    for (int jj=0;jj<2;jj++){
      int j=w*32+jj*16+c;
      float ir=ai[jj*3+0][r]+bih6[jj*3+0];
      float iz=ai[jj*3+1][r]+bih6[jj*3+1];
      float in_=ai[jj*3+2][r]+bih6[jj*3+2];
      float hr=ah[jj*3+0][r]+bhh6[jj*3+0];
      float hz=ah[jj*3+1][r]+bhh6[jj*3+1];
      float hn=ah[jj*3+2][r]+bhh6[jj*3+2];
      float rr=sigm(ir+hr), zz=sigm(iz+hz), nn=tanh_(in_+rr*hn);
      float mo=memfl[m][j];
      mem_f[(b0+m)*256+j]=(1.f-zz)*nn+zz*mo;
    }
  }
}

// ---------------------------------------------------------------------------
// Final head, all fp32.
// ---------------------------------------------------------------------------
__global__ void k_final(const float* mem_f, const float* a1f, const float* a2f,
    const float* W1o, const float* b1o, const float* W2o, const float* b2o, float* outp)
{
  __shared__ float af[768];
  __shared__ float tl[256];
  __shared__ float lg[2];
  int b=blockIdx.x, tid=threadIdx.x;
  af[tid]     = mem_f[b*256+tid];
  af[256+tid] = a1f[b*256+tid];
  af[512+tid] = a2f[b*256+tid];
  __syncthreads();
  float s=b1o[tid];
  const float* wr=W1o + (long)tid*768;
  for (int k=0;k<768;k++) s += af[k]*wr[k];
  tl[tid]=tanh_(s);
  __syncthreads();
  if (tid<2){
    float l=b2o[tid];
    const float* w2=W2o + tid*256;
    for (int k=0;k<256;k++) l += tl[k]*w2[k];
    lg[tid]=l;
  }
  __syncthreads();
  if (tid==0){
    float m=fmaxf(lg[0],lg[1]);
    float e0=__expf(lg[0]-m), e1=__expf(lg[1]-m);
    float inv=1.f/(e0+e1);
    outp[b*2]=e0*inv; outp[b*2+1]=e1*inv;
  }
}

// ---------------------------------------------------------------------------
extern "C" void kernel_launch(void* const* d_in, const int* in_sizes, int n_in,
                              void* d_out, int out_size, void* d_ws, size_t ws_size,
                              hipStream_t stream) {
  const int* c_p   = (const int*)d_in[0];
  const int* c_m   = (const int*)d_in[1];
  const int* q_p   = (const int*)d_in[2];
  const int* q_m   = (const int*)d_in[3];
  const int* a1p   = (const int*)d_in[4];
  const int* a1m   = (const int*)d_in[5];
  const int* a2p   = (const int*)d_in[6];
  const int* a2m   = (const int*)d_in[7];
  const float* embed = (const float*)d_in[8];
  const float* cWih=(const float*)d_in[9],  *cWhh=(const float*)d_in[10], *cbih=(const float*)d_in[11], *cbhh=(const float*)d_in[12];
  const float* qWih=(const float*)d_in[13], *qWhh=(const float*)d_in[14], *qbih=(const float*)d_in[15], *qbhh=(const float*)d_in[16];
  const float* aWih=(const float*)d_in[17], *aWhh=(const float*)d_in[18], *abih=(const float*)d_in[19], *abhh=(const float*)d_in[20];
  const float* tWih=(const float*)d_in[21], *tWhh=(const float*)d_in[22], *tbih=(const float*)d_in[23], *tbhh=(const float*)d_in[24];
  const float* mWih=(const float*)d_in[25], *mWhh=(const float*)d_in[26], *mbih=(const float*)d_in[27], *mbhh=(const float*)d_in[28];
  const float* gW1=(const float*)d_in[29], *gb1=(const float*)d_in[30], *gW2=(const float*)d_in[31], *gb2=(const float*)d_in[32];
  const float* oW1=(const float*)d_in[33], *ob1=(const float*)d_in[34], *oW2=(const float*)d_in[35], *ob2=(const float*)d_in[36];

  char* ws = (char*)d_ws;
  size_t off = 0;
  u16* P[10];
  for (int i=0;i<10;i++){ P[i]=(u16*)(ws+off); off+=393216; }
  u16* PgW1 =(u16*)(ws+off); off+=917504;
  float* B[10];
  for (int i=0;i<10;i++){ B[i]=(float*)(ws+off); off+=3072; }
  u16* gi_c =(u16*)(ws+off); off+=(size_t)160*SLEN*TP*2;   // 118 MB
  u16* gi_q =(u16*)(ws+off); off+=(size_t)4*QLEN*TP*2;
  u16* gi_a1=(u16*)(ws+off); off+=(size_t)4*ALEN*TP*2;
  u16* gi_a2=(u16*)(ws+off); off+=(size_t)4*ALEN*TP*2;
  u16* enc_hi=(u16*)(ws+off); off+=(size_t)SCTX*256*2;
  u16* enc_lo=(u16*)(ws+off); off+=(size_t)SCTX*256*2;
  float* enc_qf =(float*)(ws+off); off+=64*256*4;
  float* enc_a1f=(float*)(ws+off); off+=64*256*4;
  float* enc_a2f=(float*)(ws+off); off+=64*256*4;
  float* mem_f  =(float*)(ws+off); off+=64*256*4;
  float* gi_attn=(float*)(ws+off); off+=(size_t)160*TP*4;  // 7.9 MB
  float* partial=(float*)(ws+off); off+=(size_t)SCTX*256*4;
  float* gbuf   =(float*)(ws+off); off+=SCTX*4;

  k_prep<<<4751, 512, 0, stream>>>(cWih,cWhh,qWih,qWhh,aWih,aWhh,tWih,tWhh,mWih,mWhh,gW1,
      cbih,cbhh,qbih,qbhh,abih,abhh,tbih,tbhh,mbih,mbhh,
      P[0],P[1],P[2],P[3],P[4],P[5],P[6],P[7],P[8],P[9], PgW1,
      B[0],B[1],B[2],B[3],B[4],B[5],B[6],B[7],B[8],B[9]);

  k_xproj<<<1244, 512, 0, stream>>>(c_p,q_p,a1p,a2p, embed,
      P[0],P[2],P[4], B[0],B[2],B[4], gi_c,gi_q,gi_a1,gi_a2);

  k_enc_scan<<<172, 512, 0, stream>>>(c_m,q_m,a1m,a2m,
      P[1],P[3],P[5], B[1],B[3],B[5], gi_c,gi_q,gi_a1,gi_a2,
      enc_hi,enc_lo, enc_qf,enc_a1f,enc_a2f);

  k_gi<<<161, 512, 0, stream>>>(enc_hi,enc_lo, P[6], B[6], gi_attn, enc_qf, mem_f);

  k_gatepre<<<80, 512, 0, stream>>>(enc_hi,enc_lo, enc_qf, PgW1, gb1, partial);

  for (int ep=0; ep<3; ep++){
    k_gate<<<80, 512, 0, stream>>>(enc_hi,enc_lo, mem_f, partial, PgW1, gW2, gb2, gbuf);
    k_scan<<<4, 512, 0, stream>>>(P[7], B[7], gi_attn, gbuf, mem_f, P[8], P[9], B[8], B[9]);
  }

  k_final<<<64, 256, 0, stream>>>(mem_f, enc_a1f, enc_a2f, oW1, ob1, oW2, ob2, (float*)d_out);
}

// Round 9
// 878.118 us; speedup vs baseline: 1.4481x; 1.0185x over previous
//
#include <hip/hip_runtime.h>

typedef unsigned short u16;
typedef __bf16 bf16x8 __attribute__((ext_vector_type(8)));
typedef float f32x4 __attribute__((ext_vector_type(4)));
typedef float f32x4v __attribute__((ext_vector_type(4)));
typedef unsigned int u32x2 __attribute__((ext_vector_type(2)));

#define NSENT 40
#define SLEN 30
#define QLEN 20
#define ALEN 12
#define SCTX 2560
#define SLOT 24              // u16 (or fp32) values per lane-slot
#define TP 12288             // 512*24 elements per (block,t) plane

__device__ __forceinline__ float b2f(u16 u){ union{float f; unsigned i;} v; v.i = ((unsigned)u)<<16; return v.f; }
__device__ __forceinline__ u16 f2b(float f){ union{float f; unsigned u;} v; v.f=f; unsigned u=v.u; u += ((u>>16)&1u) + 0x7fffu; return (u16)(u>>16); }
__device__ __forceinline__ float sigm(float x){ return __builtin_amdgcn_rcpf(1.f + __expf(-x)); }
__device__ __forceinline__ float tanh_(float x){
  float a = fminf(fmaxf(2.f*x, -30.f), 30.f);
  float e = __expf(a);
  return 1.f - 2.f*__builtin_amdgcn_rcpf(e + 1.f);
}
__device__ __forceinline__ f32x4 mfma16(bf16x8 a, bf16x8 b, f32x4 c){
  return __builtin_amdgcn_mfma_f32_16x16x32_bf16(a, b, c, 0, 0, 0);
}

// ---------------------------------------------------------------------------
// Prep: pi-permute (n' = g16*48 + gate*16 + c <-> j = gate*256 + g16*16 + c)
// 10 weight mats -> bf16 P0..P9; gW1 plain bf16; 10 pi-permuted fp32 biases.
// ---------------------------------------------------------------------------
__global__ void k_prep(
    const float* cWih, const float* cWhh, const float* qWih, const float* qWhh,
    const float* aWih, const float* aWhh, const float* tWih, const float* tWhh,
    const float* mWih, const float* mWhh, const float* gW1,
    const float* cbih, const float* cbhh, const float* qbih, const float* qbhh,
    const float* abih, const float* abhh, const float* tbih, const float* tbhh,
    const float* mbih, const float* mbhh,
    u16* P0,u16* P1,u16* P2,u16* P3,u16* P4,u16* P5,u16* P6,u16* P7,u16* P8,u16* P9,
    u16* PgW1,
    float* B0,float* B1,float* B2,float* B3,float* B4,float* B5,float* B6,float* B7,
    float* B8,float* B9)
{
  int i = blockIdx.x*512 + threadIdx.x;   // 4751*512 = 2,432,512
  if (i < 1966080){
    int seg = i/196608; int e = i - seg*196608;
    int np = e>>8, k = e&255;
    int g16 = np/48, rem = np - g16*48, gate = rem>>4, cc = rem&15;
    int j = gate*256 + g16*16 + cc;
    const float* S; u16* D;
    switch(seg){
      case 0: S=cWih; D=P0; break; case 1: S=cWhh; D=P1; break;
      case 2: S=qWih; D=P2; break; case 3: S=qWhh; D=P3; break;
      case 4: S=aWih; D=P4; break; case 5: S=aWhh; D=P5; break;
      case 6: S=tWih; D=P6; break; case 7: S=tWhh; D=P7; break;
      case 8: S=mWih; D=P8; break; default: S=mWhh; D=P9; break;
    }
    D[e] = f2b(S[j*256 + k]);
  } else if (i < 2424832){
    int e = i - 1966080;
    PgW1[e] = f2b(gW1[e]);
  } else {
    int e = i - 2424832;                  // 7680 = 10*768
    int seg = e/768; int np = e - seg*768;
    int g16 = np/48, rem = np - g16*48, gate = rem>>4, cc = rem&15;
    int j = gate*256 + g16*16 + cc;
    const float* S; float* D;
    switch(seg){
      case 0: S=cbih; D=B0; break; case 1: S=cbhh; D=B1; break;
      case 2: S=qbih; D=B2; break; case 3: S=qbhh; D=B3; break;
      case 4: S=abih; D=B4; break; case 5: S=abhh; D=B5; break;
      case 6: S=tbih; D=B6; break; case 7: S=tbhh; D=B7; break;
      case 8: S=mbih; D=B8; break; default: S=mbhh; D=B9; break;
    }
    D[np] = S[j];
  }
}

// ---------------------------------------------------------------------------
// x-projections. 64 rows/block (32 seqs x 2 t); nt embed loads + nt gi stores
// keep the 393KB weight matrix L2-resident.
// gi plane layout: plane*TP + jj*6144 + (w8*64+lane)*12 + (r*3+g).
// ---------------------------------------------------------------------------
__global__ __launch_bounds__(512, 4) void k_xproj(
    const int* c_p, const int* q_p, const int* a1p, const int* a2p,
    const float* embed,
    const u16* cWihP, const u16* qWihP, const u16* aWihP,
    const float* cBih, const float* qBih, const float* aBih,
    u16* gi_c, u16* gi_q, u16* gi_a1, u16* gi_a2)
{
  __shared__ u16 xb[64][288];
  int bid=blockIdx.x, tid=threadIdx.x;
  const int* toks; const u16* W; const float* bias; u16* out; int T, blk32, t0;
  if (bid < 1200){ toks=c_p; W=cWihP; bias=cBih; out=gi_c; T=SLEN; blk32=bid/15; t0=(bid-blk32*15)*2; }
  else if (bid < 1220){ int e=bid-1200; toks=q_p; W=qWihP; bias=qBih; out=gi_q; T=QLEN; blk32=e/10; t0=(e-blk32*10)*2; }
  else if (bid < 1232){ int e=bid-1220; toks=a1p; W=aWihP; bias=aBih; out=gi_a1; T=ALEN; blk32=e/6; t0=(e-blk32*6)*2; }
  else               { int e=bid-1232; toks=a2p; W=aWihP; bias=aBih; out=gi_a2; T=ALEN; blk32=e/6; t0=(e-blk32*6)*2; }
  int seq0 = blk32*32;
  #pragma unroll
  for (int p=0;p<8;p++){
    int i=p*512+tid; int row=i>>6, f4=i&63;   // row wave-uniform
    int tp=row>>5, sm=row&31;
    int tok = toks[(seq0+sm)*T + t0+tp];
    f32x4v v = __builtin_nontemporal_load((const f32x4v*)(embed + (long)tok*256) + f4);
    unsigned lo = (unsigned)f2b(v[0]) | ((unsigned)f2b(v[1])<<16);
    unsigned hi = (unsigned)f2b(v[2]) | ((unsigned)f2b(v[3])<<16);
    u32x2 pk; pk.x=lo; pk.y=hi;
    *(u32x2*)&xb[row][f4*4] = pk;
  }
  const int w=tid>>6, lane=tid&63, c=lane&15, quad=lane>>4;
  __syncthreads();
  #pragma unroll
  for (int jj=0;jj<2;jj++){
    f32x4 acc[4][3];
    #pragma unroll
    for (int Mt=0;Mt<4;Mt++)
      #pragma unroll
      for (int g=0;g<3;g++) acc[Mt][g]=(f32x4){0.f,0.f,0.f,0.f};
    #pragma unroll
    for (int Kt=0;Kt<8;Kt++){
      bf16x8 a0=*(const bf16x8*)&xb[c][Kt*32+quad*8];
      bf16x8 a1=*(const bf16x8*)&xb[16+c][Kt*32+quad*8];
      bf16x8 a2=*(const bf16x8*)&xb[32+c][Kt*32+quad*8];
      bf16x8 a3=*(const bf16x8*)&xb[48+c][Kt*32+quad*8];
      #pragma unroll
      for (int g=0;g<3;g++){
        bf16x8 bfr=*(const bf16x8*)(W + (w*96+(jj*3+g)*16+c)*256 + Kt*32 + quad*8);
        acc[0][g]=mfma16(a0,bfr,acc[0][g]);
        acc[1][g]=mfma16(a1,bfr,acc[1][g]);
        acc[2][g]=mfma16(a2,bfr,acc[2][g]);
        acc[3][g]=mfma16(a3,bfr,acc[3][g]);
      }
    }
    float bv[3];
    #pragma unroll
    for (int g=0;g<3;g++) bv[g]=bias[w*96+(jj*3+g)*16+c];
    #pragma unroll
    for (int Mt=0;Mt<4;Mt++){
      int tp=Mt>>1, smh=Mt&1;
      unsigned d[6];
      #pragma unroll
      for (int k=0;k<6;k++){
        int s0=2*k, s1=2*k+1;
        int r0=s0/3, g0=s0%3, r1=s1/3, g1=s1%3;
        unsigned lo=f2b(acc[Mt][g0][r0]+bv[g0]);
        unsigned hi=f2b(acc[Mt][g1][r1]+bv[g1]);
        d[k]=lo|(hi<<16);
      }
      long block16 = (long)blk32*2 + smh;
      u16* dst = out + (block16*T + t0+tp)*TP + jj*6144 + (w*64+lane)*12;
      u32x2 s0v; s0v.x=d[0]; s0v.y=d[1];
      u32x2 s1v; s1v.x=d[2]; s1v.y=d[3];
      u32x2 s2v; s2v.x=d[4]; s2v.y=d[5];
      __builtin_nontemporal_store(s0v, (u32x2*)dst);
      __builtin_nontemporal_store(s1v, (u32x2*)(dst+4));
      __builtin_nontemporal_store(s2v, (u32x2*)(dst+8));
    }
  }
}

// ---------------------------------------------------------------------------
// Recurrent encoder scans: packed gi via 6 per-lane u32x2 loads (jj-grouped
// layout), prefetch-1, no gi LDS. 172 WGs x 16 seqs, 1 barrier/step.
// (Round-2 proven structure; VGPR cap 128 — do not restructure, rounds
// 3/5/6/7 all regressed.)
// ---------------------------------------------------------------------------
__global__ __launch_bounds__(512, 2) void k_enc_scan(
    const int* c_mask, const int* q_mask, const int* a1m, const int* a2m,
    const u16* cWhhP, const u16* qWhhP, const u16* aWhhP,
    const float* cBhh, const float* qBhh, const float* aBhh,
    const u16* gi_c, const u16* gi_q, const u16* gi_a1, const u16* gi_a2,
    u16* enc_hi, u16* enc_lo, float* enc_qf, float* enc_a1f, float* enc_a2f)
{
  __shared__ u16 hhi[16][264];
  __shared__ u16 hlo[16][264];
  __shared__ int idxs[16];
  int bid=blockIdx.x, tid=threadIdx.x;
  const int* msk; const u16* W; const float* bhh; const u16* gi; int T, seq0, mode;
  u16 *ohi=0, *olo=0; float* of=0;
  if (bid<160){ msk=c_mask; W=cWhhP; bhh=cBhh; gi=gi_c+(long)bid*SLEN*TP; T=SLEN; seq0=bid*16; mode=0; ohi=enc_hi; olo=enc_lo; }
  else if (bid<164){ int e=bid-160; msk=q_mask; W=qWhhP; bhh=qBhh; gi=gi_q+(long)e*QLEN*TP; T=QLEN; seq0=e*16; mode=1; of=enc_qf; }
  else if (bid<168){ int e=bid-164; msk=a1m; W=aWhhP; bhh=aBhh; gi=gi_a1+(long)e*ALEN*TP; T=ALEN; seq0=e*16; mode=1; of=enc_a1f; }
  else             { int e=bid-168; msk=a2m; W=aWhhP; bhh=aBhh; gi=gi_a2+(long)e*ALEN*TP; T=ALEN; seq0=e*16; mode=1; of=enc_a2f; }
  if (tid<16){
    int len=0; const int* mr=msk+(seq0+tid)*T;
    for (int t=0;t<T;t++) len += (mr[t]==0);
    int id=len-1; if(id<0)id=0; if(id>T-1)id=T-1; idxs[tid]=id;
  }
  for (int i=tid;i<16*264;i+=512){ ((u16*)hhi)[i]=0; ((u16*)hlo)[i]=0; }
  const int w=tid>>6, lane=tid&63, c=lane&15, quad=lane>>4;
  float biasv[6];
  #pragma unroll
  for (int nt=0;nt<6;nt++) biasv[nt]=bhh[w*96+nt*16+c];
  uint4 breg[48];
  #pragma unroll
  for (int nt=0;nt<6;nt++)
    #pragma unroll
    for (int Kt=0;Kt<8;Kt++)
      breg[nt*8+Kt] = *(const uint4*)(W + (w*96+nt*16+c)*256 + Kt*32 + quad*8);
  float hreg[8];
  #pragma unroll
  for (int i=0;i<8;i++) hreg[i]=0.f;
  const u16* gp = gi + (w*64+lane)*12;
  u32x2 pA0=*(const u32x2*)(gp),      pA1=*(const u32x2*)(gp+4),    pA2=*(const u32x2*)(gp+8);
  u32x2 pA3=*(const u32x2*)(gp+6144), pA4=*(const u32x2*)(gp+6148), pA5=*(const u32x2*)(gp+6152);
  __syncthreads();
  int idxr[4];
  #pragma unroll
  for (int r=0;r<4;r++) idxr[r]=idxs[quad*4+r];

  for (int t=0;t<T;t++){
    u32x2 pB0,pB1,pB2,pB3,pB4,pB5;
    bool pf=(t+1<T);
    if (pf){
      const u16* gn = gp + (long)(t+1)*TP;
      pB0=*(const u32x2*)(gn);      pB1=*(const u32x2*)(gn+4);    pB2=*(const u32x2*)(gn+8);
      pB3=*(const u32x2*)(gn+6144); pB4=*(const u32x2*)(gn+6148); pB5=*(const u32x2*)(gn+6152);
    }
    f32x4 acc[6];
    #pragma unroll
    for (int nt=0;nt<6;nt++) acc[nt]=(f32x4){0.f,0.f,0.f,0.f};
    #pragma unroll
    for (int Kt=0;Kt<8;Kt++){
      bf16x8 a=*(const bf16x8*)&hhi[c][Kt*32+quad*8];
      #pragma unroll
      for (int nt=0;nt<6;nt++) acc[nt]=mfma16(a,*(const bf16x8*)&breg[nt*8+Kt],acc[nt]);
    }
    #pragma unroll
    for (int Kt=0;Kt<8;Kt++){
      bf16x8 a=*(const bf16x8*)&hlo[c][Kt*32+quad*8];
      #pragma unroll
      for (int nt=0;nt<6;nt++) acc[nt]=mfma16(a,*(const bf16x8*)&breg[nt*8+Kt],acc[nt]);
    }
    unsigned pd[12];
    *(u32x2*)&pd[0]=pA0; *(u32x2*)&pd[2]=pA1; *(u32x2*)&pd[4]=pA2;
    *(u32x2*)&pd[6]=pA3; *(u32x2*)&pd[8]=pA4; *(u32x2*)&pd[10]=pA5;
    #pragma unroll
    for (int r=0;r<4;r++){
      int m=quad*4+r;
      #pragma unroll
      for (int jj=0;jj<2;jj++){
        int j=w*32+jj*16+c;
        int ib=r*3;   // slot within jj region; words at pd[jj*6 + ...]
        float ir = b2f((u16)((pd[jj*6+(ib>>1)]     >> ((ib&1)*16)) & 0xffffu));
        float iz = b2f((u16)((pd[jj*6+((ib+1)>>1)] >> (((ib+1)&1)*16)) & 0xffffu));
        float in_= b2f((u16)((pd[jj*6+((ib+2)>>1)] >> (((ib+2)&1)*16)) & 0xffffu));
        float hr=acc[jj*3+0][r]+biasv[jj*3+0];
        float hz=acc[jj*3+1][r]+biasv[jj*3+1];
        float hn=acc[jj*3+2][r]+biasv[jj*3+2];
        float rr=sigm(ir+hr), zz=sigm(iz+hz), nn=tanh_(in_+rr*hn);
        float ho=hreg[r*2+jj];
        float hnew=(1.f-zz)*nn+zz*ho;
        hreg[r*2+jj]=hnew;
        u16 hi_=f2b(hnew); u16 lo_=f2b(hnew-b2f(hi_));
        hhi[m][j]=hi_; hlo[m][j]=lo_;
        if (t==idxr[r]){
          long o=(long)(seq0+m)*256+j;
          if (mode==0){ ohi[o]=hi_; olo[o]=lo_; }
          else of[o]=hnew;
        }
      }
    }
    __syncthreads();
    pA0=pB0; pA1=pB1; pA2=pB2; pA3=pB3; pA4=pB4; pA5=pB5;
  }
}

// ---------------------------------------------------------------------------
// gi_attn packed fp32: WG = (b-block of 16, sentence s). 160 WGs + init WG.
// Slot: gi_attn[(bblk*40+s)*TP + (w*64+lane)*24 + (r*2+jj)*3+gate]
// ---------------------------------------------------------------------------
__global__ __launch_bounds__(512, 2) void k_gi(
    const u16* enc_hi, const u16* enc_lo, const u16* tWihP, const float* tBih,
    float* gi_attn, const float* enc_qf, float* mem_f)
{
  int bid=blockIdx.x, tid=threadIdx.x;
  if (bid==160){ for (int i=tid;i<64*256;i+=512) mem_f[i]=enc_qf[i]; return; }
  __shared__ u16 ahi[16][264];
  __shared__ u16 alo[16][264];
  int bblk=bid/40, s=bid-bblk*40, b0=bblk*16;
  {
    int row=tid>>5, ch=tid&31;
    long seq=(long)(b0+row)*NSENT + s;
    *(uint4*)((char*)&ahi[row][0]+ch*16) = *((const uint4*)(enc_hi+seq*256)+ch);
    *(uint4*)((char*)&alo[row][0]+ch*16) = *((const uint4*)(enc_lo+seq*256)+ch);
  }
  const int w=tid>>6, lane=tid&63, c=lane&15, quad=lane>>4;
  f32x4 acc[6];
  #pragma unroll
  for (int nt=0;nt<6;nt++) acc[nt]=(f32x4){0.f,0.f,0.f,0.f};
  __syncthreads();
  #pragma unroll
  for (int Kt=0;Kt<8;Kt++){
    bf16x8 a=*(const bf16x8*)&ahi[c][Kt*32+quad*8];
    #pragma unroll
    for (int nt=0;nt<6;nt++){
      bf16x8 bfr=*(const bf16x8*)(tWihP + (w*96+nt*16+c)*256 + Kt*32 + quad*8);
      acc[nt]=mfma16(a,bfr,acc[nt]);
    }
  }
  #pragma unroll
  for (int Kt=0;Kt<8;Kt++){
    bf16x8 a=*(const bf16x8*)&alo[c][Kt*32+quad*8];
    #pragma unroll
    for (int nt=0;nt<6;nt++){
      bf16x8 bfr=*(const bf16x8*)(tWihP + (w*96+nt*16+c)*256 + Kt*32 + quad*8);
      acc[nt]=mfma16(a,bfr,acc[nt]);
    }
  }
  float biasv[6];
  #pragma unroll
  for (int nt=0;nt<6;nt++) biasv[nt]=tBih[w*96+nt*16+c];
  float* dst = gi_attn + ((long)(bblk*40+s))*TP + (w*64+lane)*SLOT;
  #pragma unroll
  for (int d=0;d<6;d++){
    float4 v;
    #pragma unroll
    for (int e=0;e<4;e++){
      int idx=4*d+e;
      int r=idx/6, rem=idx%6, jj=rem/3, g=rem%3;
      ((float*)&v)[e]=acc[jj*3+g][r]+biasv[jj*3+g];
    }
    *(float4*)(dst+4*d)=v;
  }
}

// ---------------------------------------------------------------------------
// Gate precompute, n-split: 160 blocks = (80 seq-groups x 2 n-halves).
// Each wave owns ONE 16-col n-group: n = nh*128 + w*16 + c. MFMA/wave 128->64.
// Writes its disjoint n-half of partial (no reduction needed).
// ---------------------------------------------------------------------------
__global__ __launch_bounds__(512, 1) void k_gatepre(
    const u16* enc_hi, const u16* enc_lo, const float* enc_qf,
    const u16* W1, const float* b1, float* partial)
{
  __shared__ float ctf[32][257];
  __shared__ float qvf[32][257];
  __shared__ u16 ab[32][264];
  int bid=blockIdx.x, tid=threadIdx.x;
  int seqgrp=bid>>1, nh=bid&1, seq0=seqgrp*32;
  #pragma unroll
  for (int p=0;p<16;p++){
    int i=p*512+tid; int row=i>>8, j=i&255;
    int grow=seq0+row; int b=grow/NSENT;
    ctf[row][j]=b2f(enc_hi[(long)grow*256+j])+b2f(enc_lo[(long)grow*256+j]);
    qvf[row][j]=enc_qf[b*256+j];
  }
  const int w=tid>>6, lane=tid&63, c=lane&15, quad=lane>>4;
  const int n = nh*128 + w*16 + c;
  f32x4 acc[2];
  {
    float bv=b1[n];
    acc[0]=(f32x4){bv,bv,bv,bv}; acc[1]=acc[0];
  }
  const int chl[4]={0,2,3,5};
  for (int ci=0; ci<4; ci++){
    int ch=chl[ci];
    __syncthreads();
    #pragma unroll
    for (int p=0;p<16;p++){
      int i=p*512+tid; int row=i>>8, j=i&255;
      float ct=ctf[row][j], qv=qvf[row][j];
      float v;
      if      (ch==0) v=ct;
      else if (ch==2) v=qv;
      else if (ch==3) v=ct*qv;
      else            v=fabsf(ct-qv);
      ab[row][j]=f2b(v);
    }
    __syncthreads();
    #pragma unroll
    for (int Kt=0;Kt<8;Kt++){
      bf16x8 a0=*(const bf16x8*)&ab[c][Kt*32+quad*8];
      bf16x8 a1=*(const bf16x8*)&ab[16+c][Kt*32+quad*8];
      bf16x8 bfr=*(const bf16x8*)(W1 + (long)n*1792 + ch*256 + Kt*32 + quad*8);
      acc[0]=mfma16(a0,bfr,acc[0]);
      acc[1]=mfma16(a1,bfr,acc[1]);
    }
  }
  #pragma unroll
  for (int Mt=0;Mt<2;Mt++)
    #pragma unroll
    for (int r=0;r<4;r++)
      partial[(long)(seq0+Mt*16+quad*4+r)*256 + n] = acc[Mt][r];
}

// ---------------------------------------------------------------------------
// Per-episode gate, n-split: 160 blocks = (80 seq-groups x 2 n-halves).
// Each block computes its 128-n half-sum of tanh(.)*W2 and atomicAdd's into
// g (zeroed by memsetAsync before launch). b2 + sigmoid applied in k_scan.
// ---------------------------------------------------------------------------
__global__ __launch_bounds__(512, 1) void k_gate(
    const u16* enc_hi, const u16* enc_lo, const float* mem_f,
    const float* partial, const u16* W1, const float* W2, float* g)
{
  __shared__ float ctf[32][257];
  __shared__ float mvf[32][257];
  __shared__ u16 ab[32][264];
  __shared__ float pl[32][8];
  int bid=blockIdx.x, tid=threadIdx.x;
  int seqgrp=bid>>1, nh=bid&1, seq0=seqgrp*32;
  #pragma unroll
  for (int p=0;p<16;p++){
    int i=p*512+tid; int row=i>>8, j=i&255;
    int grow=seq0+row; int b=grow/NSENT;
    ctf[row][j]=b2f(enc_hi[(long)grow*256+j])+b2f(enc_lo[(long)grow*256+j]);
    mvf[row][j]=mem_f[b*256+j];
  }
  const int w=tid>>6, lane=tid&63, c=lane&15, quad=lane>>4;
  const int n = nh*128 + w*16 + c;
  f32x4 acc[2];
  float w2v=W2[n];
  #pragma unroll
  for (int Mt=0;Mt<2;Mt++)
    #pragma unroll
    for (int r=0;r<4;r++)
      acc[Mt][r]=partial[(long)(seq0+Mt*16+quad*4+r)*256 + n];
  const int chl[3]={1,4,6};
  for (int ci=0; ci<3; ci++){
    int ch=chl[ci];
    __syncthreads();
    #pragma unroll
    for (int p=0;p<16;p++){
      int i=p*512+tid; int row=i>>8, j=i&255;
      float ct=ctf[row][j], mv=mvf[row][j];
      float v;
      if      (ch==1) v=mv;
      else if (ch==4) v=ct*mv;
      else            v=fabsf(ct-mv);
      ab[row][j]=f2b(v);
    }
    __syncthreads();
    #pragma unroll
    for (int Kt=0;Kt<8;Kt++){
      bf16x8 a0=*(const bf16x8*)&ab[c][Kt*32+quad*8];
      bf16x8 a1=*(const bf16x8*)&ab[16+c][Kt*32+quad*8];
      bf16x8 bfr=*(const bf16x8*)(W1 + (long)n*1792 + ch*256 + Kt*32 + quad*8);
      acc[0]=mfma16(a0,bfr,acc[0]);
      acc[1]=mfma16(a1,bfr,acc[1]);
    }
  }
  float pm[8];
  #pragma unroll
  for (int i=0;i<8;i++){
    int Mt=i>>2, r=i&3;
    pm[i]=tanh_(acc[Mt][r])*w2v;
  }
  #pragma unroll
  for (int off=1;off<16;off<<=1)
    #pragma unroll
    for (int i=0;i<8;i++) pm[i]+=__shfl_xor(pm[i],off,64);
  if (c==0){
    #pragma unroll
    for (int i=0;i<8;i++){ int m=(i>>2)*16+quad*4+(i&3); pl[m][w]=pm[i]; }
  }
  __syncthreads();
  if (tid<32){
    float s=0.f;
    #pragma unroll
    for (int ww=0;ww<8;ww++) s+=pl[tid][ww];
    atomicAdd(&g[seq0+tid], s);
  }
}

// ---------------------------------------------------------------------------
// Episodic scan: 4 WGs x 16 batch rows; attn_Whh' VGPR-resident; packed
// gi_attn prefetch; all-lane elementwise; pi mem-GRU tail (lane-local).
// gl staging applies sigm(g + b2) (gate's sigmoid deferred here).
// ---------------------------------------------------------------------------
__global__ __launch_bounds__(512, 2) void k_scan(
    const u16* tWhhP, const float* tBhh,
    const float* gi_attn, const float* g, const float* gb2,
    float* mem_f, const u16* mWihP, const u16* mWhhP,
    const float* mBih, const float* mBhh)
{
  __shared__ u16 hb[16][264];
  __shared__ u16 mhi[16][264];
  __shared__ u16 mlo[16][264];
  __shared__ float memfl[16][256];
  __shared__ float gl[16][40];
  int bid=blockIdx.x, tid=threadIdx.x, b0=bid*16;
  const int w=tid>>6, lane=tid&63, c=lane&15, quad=lane>>4;
  for (int i=tid;i<16*264;i+=512){ ((u16*)hb)[i]=0; }
  for (int i=tid;i<4096;i+=512){
    int m=i>>8, j=i&255;
    float v=mem_f[(b0+m)*256+j]; memfl[m][j]=v;
    u16 hi_=f2b(v); mhi[m][j]=hi_; mlo[m][j]=f2b(v-b2f(hi_));
  }
  {
    float b2s = gb2[0];
    for (int i=tid;i<640;i+=512){ int m=i/40, s=i-m*40; gl[m][s]=sigm(g[(b0+m)*40+s]+b2s); }
  }
  float biasv[6];
  #pragma unroll
  for (int nt=0;nt<6;nt++) biasv[nt]=tBhh[w*96+nt*16+c];
  uint4 breg[48];
  #pragma unroll
  for (int nt=0;nt<6;nt++)
    #pragma unroll
    for (int Kt=0;Kt<8;Kt++)
      breg[nt*8+Kt] = *(const uint4*)(tWhhP + (w*96+nt*16+c)*256 + Kt*32 + quad*8);
  float hreg[8];
  #pragma unroll
  for (int i=0;i<8;i++) hreg[i]=0.f;
  const float* gp = gi_attn + ((long)bid*NSENT)*TP + (w*64+lane)*SLOT;
  float4 pA[6];
  #pragma unroll
  for (int d=0;d<6;d++) pA[d]=*(const float4*)(gp+4*d);
  __syncthreads();

  for (int s=0;s<NSENT;s++){
    float4 pB[6];
    bool pf=(s+1<NSENT);
    if (pf){
      const float* gn = gp + (long)(s+1)*TP;
      #pragma unroll
      for (int d=0;d<6;d++) pB[d]=*(const float4*)(gn+4*d);
    }
    f32x4 acc[6];
    #pragma unroll
    for (int nt=0;nt<6;nt++) acc[nt]=(f32x4){0.f,0.f,0.f,0.f};
    #pragma unroll
    for (int Kt=0;Kt<8;Kt++){
      bf16x8 a=*(const bf16x8*)&hb[c][Kt*32+quad*8];
      #pragma unroll
      for (int nt=0;nt<6;nt++) acc[nt]=mfma16(a,*(const bf16x8*)&breg[nt*8+Kt],acc[nt]);
    }
    const float* pf32 = (const float*)&pA[0];
    #pragma unroll
    for (int r=0;r<4;r++){
      int m=quad*4+r;
      float gv = gl[m][s];
      #pragma unroll
      for (int jj=0;jj<2;jj++){
        int j=w*32+jj*16+c;
        int ib=(r*2+jj)*3;
        float ir=pf32[ib], iz=pf32[ib+1], in_=pf32[ib+2];
        float hr=acc[jj*3+0][r]+biasv[jj*3+0];
        float hz=acc[jj*3+1][r]+biasv[jj*3+1];
        float hn=acc[jj*3+2][r]+biasv[jj*3+2];
        float rr=sigm(ir+hr), zz=sigm(iz+hz), nn=tanh_(in_+rr*hn);
        float ho=hreg[r*2+jj];
        float hc=(1.f-zz)*nn+zz*ho;
        float hnew=gv*hc+(1.f-gv)*ho;
        hreg[r*2+jj]=hnew;
        hb[m][j]=f2b(hnew);
      }
    }
    __syncthreads();
    #pragma unroll
    for (int d=0;d<6;d++) pA[d]=pB[d];
  }
  // memory GRU, pi layout: ai = e@mWih'^T, ah = mem(hi+lo)@mWhh'^T
  f32x4 ai[6], ah[6];
  #pragma unroll
  for (int nt=0;nt<6;nt++){ ai[nt]=(f32x4){0.f,0.f,0.f,0.f}; ah[nt]=ai[nt]; }
  #pragma unroll
  for (int Kt=0;Kt<8;Kt++){
    bf16x8 a=*(const bf16x8*)&hb[c][Kt*32+quad*8];
    #pragma unroll
    for (int nt=0;nt<6;nt++){
      bf16x8 bfr=*(const bf16x8*)(mWihP + (w*96+nt*16+c)*256 + Kt*32 + quad*8);
      ai[nt]=mfma16(a,bfr,ai[nt]);
    }
  }
  #pragma unroll
  for (int Kt=0;Kt<8;Kt++){
    bf16x8 a=*(const bf16x8*)&mhi[c][Kt*32+quad*8];
    #pragma unroll
    for (int nt=0;nt<6;nt++){
      bf16x8 bfr=*(const bf16x8*)(mWhhP + (w*96+nt*16+c)*256 + Kt*32 + quad*8);
      ah[nt]=mfma16(a,bfr,ah[nt]);
    }
  }
  #pragma unroll
  for (int Kt=0;Kt<8;Kt++){
    bf16x8 a=*(const bf16x8*)&mlo[c][Kt*32+quad*8];
    #pragma unroll
    for (int nt=0;nt<6;nt++){
      bf16x8 bfr=*(const bf16x8*)(mWhhP + (w*96+nt*16+c)*256 + Kt*32 + quad*8);
      ah[nt]=mfma16(a,bfr,ah[nt]);
    }
  }
  float bih6[6], bhh6[6];
  #pragma unroll
  for (int nt=0;nt<6;nt++){ bih6[nt]=mBih[w*96+nt*16+c]; bhh6[nt]=mBhh[w*96+nt*16+c]; }
  #pragma unroll
  for (int r=0;r<4;r++){
    int m=quad*4+r;
    #pragma unroll
    for (int jj=0;jj<2;jj++){
      int j=w*32+jj*16+c;
      float ir=ai[jj*3+0][r]+bih6[jj*3+0];
      float iz=ai[jj*3+1][r]+bih6[jj*3+1];
      float in_=ai[jj*3+2][r]+bih6[jj*3+2];
      float hr=ah[jj*3+0][r]+bhh6[jj*3+0];
      float hz=ah[jj*3+1][r]+bhh6[jj*3+1];
      float hn=ah[jj*3+2][r]+bhh6[jj*3+2];
      float rr=sigm(ir+hr), zz=sigm(iz+hz), nn=tanh_(in_+rr*hn);
      float mo=memfl[m][j];
      mem_f[(b0+m)*256+j]=(1.f-zz)*nn+zz*mo;
    }
  }
}

// ---------------------------------------------------------------------------
// Final head, all fp32.
// ---------------------------------------------------------------------------
__global__ void k_final(const float* mem_f, const float* a1f, const float* a2f,
    const float* W1o, const float* b1o, const float* W2o, const float* b2o, float* outp)
{
  __shared__ float af[768];
  __shared__ float tl[256];
  __shared__ float lg[2];
  int b=blockIdx.x, tid=threadIdx.x;
  af[tid]     = mem_f[b*256+tid];
  af[256+tid] = a1f[b*256+tid];
  af[512+tid] = a2f[b*256+tid];
  __syncthreads();
  float s=b1o[tid];
  const float* wr=W1o + (long)tid*768;
  for (int k=0;k<768;k++) s += af[k]*wr[k];
  tl[tid]=tanh_(s);
  __syncthreads();
  if (tid<2){
    float l=b2o[tid];
    const float* w2=W2o + tid*256;
    for (int k=0;k<256;k++) l += tl[k]*w2[k];
    lg[tid]=l;
  }
  __syncthreads();
  if (tid==0){
    float m=fmaxf(lg[0],lg[1]);
    float e0=__expf(lg[0]-m), e1=__expf(lg[1]-m);
    float inv=1.f/(e0+e1);
    outp[b*2]=e0*inv; outp[b*2+1]=e1*inv;
  }
}

// ---------------------------------------------------------------------------
extern "C" void kernel_launch(void* const* d_in, const int* in_sizes, int n_in,
                              void* d_out, int out_size, void* d_ws, size_t ws_size,
                              hipStream_t stream) {
  const int* c_p   = (const int*)d_in[0];
  const int* c_m   = (const int*)d_in[1];
  const int* q_p   = (const int*)d_in[2];
  const int* q_m   = (const int*)d_in[3];
  const int* a1p   = (const int*)d_in[4];
  const int* a1m   = (const int*)d_in[5];
  const int* a2p   = (const int*)d_in[6];
  const int* a2m   = (const int*)d_in[7];
  const float* embed = (const float*)d_in[8];
  const float* cWih=(const float*)d_in[9],  *cWhh=(const float*)d_in[10], *cbih=(const float*)d_in[11], *cbhh=(const float*)d_in[12];
  const float* qWih=(const float*)d_in[13], *qWhh=(const float*)d_in[14], *qbih=(const float*)d_in[15], *qbhh=(const float*)d_in[16];
  const float* aWih=(const float*)d_in[17], *aWhh=(const float*)d_in[18], *abih=(const float*)d_in[19], *abhh=(const float*)d_in[20];
  const float* tWih=(const float*)d_in[21], *tWhh=(const float*)d_in[22], *tbih=(const float*)d_in[23], *tbhh=(const float*)d_in[24];
  const float* mWih=(const float*)d_in[25], *mWhh=(const float*)d_in[26], *mbih=(const float*)d_in[27], *mbhh=(const float*)d_in[28];
  const float* gW1=(const float*)d_in[29], *gb1=(const float*)d_in[30], *gW2=(const float*)d_in[31], *gb2=(const float*)d_in[32];
  const float* oW1=(const float*)d_in[33], *ob1=(const float*)d_in[34], *oW2=(const float*)d_in[35], *ob2=(const float*)d_in[36];

  char* ws = (char*)d_ws;
  size_t off = 0;
  u16* P[10];
  for (int i=0;i<10;i++){ P[i]=(u16*)(ws+off); off+=393216; }
  u16* PgW1 =(u16*)(ws+off); off+=917504;
  float* B[10];
  for (int i=0;i<10;i++){ B[i]=(float*)(ws+off); off+=3072; }
  u16* gi_c =(u16*)(ws+off); off+=(size_t)160*SLEN*TP*2;   // 118 MB
  u16* gi_q =(u16*)(ws+off); off+=(size_t)4*QLEN*TP*2;
  u16* gi_a1=(u16*)(ws+off); off+=(size_t)4*ALEN*TP*2;
  u16* gi_a2=(u16*)(ws+off); off+=(size_t)4*ALEN*TP*2;
  u16* enc_hi=(u16*)(ws+off); off+=(size_t)SCTX*256*2;
  u16* enc_lo=(u16*)(ws+off); off+=(size_t)SCTX*256*2;
  float* enc_qf =(float*)(ws+off); off+=64*256*4;
  float* enc_a1f=(float*)(ws+off); off+=64*256*4;
  float* enc_a2f=(float*)(ws+off); off+=64*256*4;
  float* mem_f  =(float*)(ws+off); off+=64*256*4;
  float* gi_attn=(float*)(ws+off); off+=(size_t)160*TP*4;  // 7.9 MB
  float* partial=(float*)(ws+off); off+=(size_t)SCTX*256*4;
  float* gbuf   =(float*)(ws+off); off+=SCTX*4;

  k_prep<<<4751, 512, 0, stream>>>(cWih,cWhh,qWih,qWhh,aWih,aWhh,tWih,tWhh,mWih,mWhh,gW1,
      cbih,cbhh,qbih,qbhh,abih,abhh,tbih,tbhh,mbih,mbhh,
      P[0],P[1],P[2],P[3],P[4],P[5],P[6],P[7],P[8],P[9], PgW1,
      B[0],B[1],B[2],B[3],B[4],B[5],B[6],B[7],B[8],B[9]);

  k_xproj<<<1244, 512, 0, stream>>>(c_p,q_p,a1p,a2p, embed,
      P[0],P[2],P[4], B[0],B[2],B[4], gi_c,gi_q,gi_a1,gi_a2);

  k_enc_scan<<<172, 512, 0, stream>>>(c_m,q_m,a1m,a2m,
      P[1],P[3],P[5], B[1],B[3],B[5], gi_c,gi_q,gi_a1,gi_a2,
      enc_hi,enc_lo, enc_qf,enc_a1f,enc_a2f);

  k_gi<<<161, 512, 0, stream>>>(enc_hi,enc_lo, P[6], B[6], gi_attn, enc_qf, mem_f);

  k_gatepre<<<160, 512, 0, stream>>>(enc_hi,enc_lo, enc_qf, PgW1, gb1, partial);

  for (int ep=0; ep<3; ep++){
    hipMemsetAsync(gbuf, 0, SCTX*4, stream);
    k_gate<<<160, 512, 0, stream>>>(enc_hi,enc_lo, mem_f, partial, PgW1, gW2, gbuf);
    k_scan<<<4, 512, 0, stream>>>(P[7], B[7], gi_attn, gbuf, gb2, mem_f, P[8], P[9], B[8], B[9]);
  }

  k_final<<<64, 256, 0, stream>>>(mem_f, enc_a1f, enc_a2f, oW1, ob1, oW2, ob2, (float*)d_out);
}

// Round 10
// 867.623 us; speedup vs baseline: 1.4657x; 1.0121x over previous
//
#include <hip/hip_runtime.h>

typedef unsigned short u16;
typedef __bf16 bf16x8 __attribute__((ext_vector_type(8)));
typedef float f32x4 __attribute__((ext_vector_type(4)));
typedef float f32x4v __attribute__((ext_vector_type(4)));
typedef unsigned int u32x2 __attribute__((ext_vector_type(2)));

#define NSENT 40
#define SLEN 30
#define QLEN 20
#define ALEN 12
#define SCTX 2560
#define SLOT 24              // u16 (or fp32) values per lane-slot
#define TP 12288             // 512*24 elements per (block,t) plane

__device__ __forceinline__ float b2f(u16 u){ union{float f; unsigned i;} v; v.i = ((unsigned)u)<<16; return v.f; }
__device__ __forceinline__ u16 f2b(float f){ union{float f; unsigned u;} v; v.f=f; unsigned u=v.u; u += ((u>>16)&1u) + 0x7fffu; return (u16)(u>>16); }
__device__ __forceinline__ float sigm(float x){ return __builtin_amdgcn_rcpf(1.f + __expf(-x)); }
__device__ __forceinline__ float tanh_(float x){
  float a = fminf(fmaxf(2.f*x, -30.f), 30.f);
  float e = __expf(a);
  return 1.f - 2.f*__builtin_amdgcn_rcpf(e + 1.f);
}
__device__ __forceinline__ f32x4 mfma16(bf16x8 a, bf16x8 b, f32x4 c){
  return __builtin_amdgcn_mfma_f32_16x16x32_bf16(a, b, c, 0, 0, 0);
}

// ---------------------------------------------------------------------------
// Prep: pi-permute (n' = g16*48 + gate*16 + c <-> j = gate*256 + g16*16 + c)
// 10 weight mats -> bf16 P0..P9; gW1 plain bf16; 10 pi-permuted fp32 biases.
// ---------------------------------------------------------------------------
__global__ void k_prep(
    const float* cWih, const float* cWhh, const float* qWih, const float* qWhh,
    const float* aWih, const float* aWhh, const float* tWih, const float* tWhh,
    const float* mWih, const float* mWhh, const float* gW1,
    const float* cbih, const float* cbhh, const float* qbih, const float* qbhh,
    const float* abih, const float* abhh, const float* tbih, const float* tbhh,
    const float* mbih, const float* mbhh,
    u16* P0,u16* P1,u16* P2,u16* P3,u16* P4,u16* P5,u16* P6,u16* P7,u16* P8,u16* P9,
    u16* PgW1,
    float* B0,float* B1,float* B2,float* B3,float* B4,float* B5,float* B6,float* B7,
    float* B8,float* B9)
{
  int i = blockIdx.x*512 + threadIdx.x;   // 4751*512 = 2,432,512
  if (i < 1966080){
    int seg = i/196608; int e = i - seg*196608;
    int np = e>>8, k = e&255;
    int g16 = np/48, rem = np - g16*48, gate = rem>>4, cc = rem&15;
    int j = gate*256 + g16*16 + cc;
    const float* S; u16* D;
    switch(seg){
      case 0: S=cWih; D=P0; break; case 1: S=cWhh; D=P1; break;
      case 2: S=qWih; D=P2; break; case 3: S=qWhh; D=P3; break;
      case 4: S=aWih; D=P4; break; case 5: S=aWhh; D=P5; break;
      case 6: S=tWih; D=P6; break; case 7: S=tWhh; D=P7; break;
      case 8: S=mWih; D=P8; break; default: S=mWhh; D=P9; break;
    }
    D[e] = f2b(S[j*256 + k]);
  } else if (i < 2424832){
    int e = i - 1966080;
    PgW1[e] = f2b(gW1[e]);
  } else {
    int e = i - 2424832;                  // 7680 = 10*768
    int seg = e/768; int np = e - seg*768;
    int g16 = np/48, rem = np - g16*48, gate = rem>>4, cc = rem&15;
    int j = gate*256 + g16*16 + cc;
    const float* S; float* D;
    switch(seg){
      case 0: S=cbih; D=B0; break; case 1: S=cbhh; D=B1; break;
      case 2: S=qbih; D=B2; break; case 3: S=qbhh; D=B3; break;
      case 4: S=abih; D=B4; break; case 5: S=abhh; D=B5; break;
      case 6: S=tbih; D=B6; break; case 7: S=tbhh; D=B7; break;
      case 8: S=mbih; D=B8; break; default: S=mbhh; D=B9; break;
    }
    D[np] = S[j];
  }
}

// ---------------------------------------------------------------------------
// x-projections. 64 rows/block (32 seqs x 2 t); nt embed loads + nt gi stores
// keep the 393KB weight matrix L2-resident.
// gi plane layout: plane*TP + jj*6144 + (w8*64+lane)*12 + (r*3+g).
// ---------------------------------------------------------------------------
__global__ __launch_bounds__(512, 4) void k_xproj(
    const int* c_p, const int* q_p, const int* a1p, const int* a2p,
    const float* embed,
    const u16* cWihP, const u16* qWihP, const u16* aWihP,
    const float* cBih, const float* qBih, const float* aBih,
    u16* gi_c, u16* gi_q, u16* gi_a1, u16* gi_a2)
{
  __shared__ u16 xb[64][288];
  int bid=blockIdx.x, tid=threadIdx.x;
  const int* toks; const u16* W; const float* bias; u16* out; int T, blk32, t0;
  if (bid < 1200){ toks=c_p; W=cWihP; bias=cBih; out=gi_c; T=SLEN; blk32=bid/15; t0=(bid-blk32*15)*2; }
  else if (bid < 1220){ int e=bid-1200; toks=q_p; W=qWihP; bias=qBih; out=gi_q; T=QLEN; blk32=e/10; t0=(e-blk32*10)*2; }
  else if (bid < 1232){ int e=bid-1220; toks=a1p; W=aWihP; bias=aBih; out=gi_a1; T=ALEN; blk32=e/6; t0=(e-blk32*6)*2; }
  else               { int e=bid-1232; toks=a2p; W=aWihP; bias=aBih; out=gi_a2; T=ALEN; blk32=e/6; t0=(e-blk32*6)*2; }
  int seq0 = blk32*32;
  #pragma unroll
  for (int p=0;p<8;p++){
    int i=p*512+tid; int row=i>>6, f4=i&63;   // row wave-uniform
    int tp=row>>5, sm=row&31;
    int tok = toks[(seq0+sm)*T + t0+tp];
    f32x4v v = __builtin_nontemporal_load((const f32x4v*)(embed + (long)tok*256) + f4);
    unsigned lo = (unsigned)f2b(v[0]) | ((unsigned)f2b(v[1])<<16);
    unsigned hi = (unsigned)f2b(v[2]) | ((unsigned)f2b(v[3])<<16);
    u32x2 pk; pk.x=lo; pk.y=hi;
    *(u32x2*)&xb[row][f4*4] = pk;
  }
  const int w=tid>>6, lane=tid&63, c=lane&15, quad=lane>>4;
  __syncthreads();
  #pragma unroll
  for (int jj=0;jj<2;jj++){
    f32x4 acc[4][3];
    #pragma unroll
    for (int Mt=0;Mt<4;Mt++)
      #pragma unroll
      for (int g=0;g<3;g++) acc[Mt][g]=(f32x4){0.f,0.f,0.f,0.f};
    #pragma unroll
    for (int Kt=0;Kt<8;Kt++){
      bf16x8 a0=*(const bf16x8*)&xb[c][Kt*32+quad*8];
      bf16x8 a1=*(const bf16x8*)&xb[16+c][Kt*32+quad*8];
      bf16x8 a2=*(const bf16x8*)&xb[32+c][Kt*32+quad*8];
      bf16x8 a3=*(const bf16x8*)&xb[48+c][Kt*32+quad*8];
      #pragma unroll
      for (int g=0;g<3;g++){
        bf16x8 bfr=*(const bf16x8*)(W + (w*96+(jj*3+g)*16+c)*256 + Kt*32 + quad*8);
        acc[0][g]=mfma16(a0,bfr,acc[0][g]);
        acc[1][g]=mfma16(a1,bfr,acc[1][g]);
        acc[2][g]=mfma16(a2,bfr,acc[2][g]);
        acc[3][g]=mfma16(a3,bfr,acc[3][g]);
      }
    }
    float bv[3];
    #pragma unroll
    for (int g=0;g<3;g++) bv[g]=bias[w*96+(jj*3+g)*16+c];
    #pragma unroll
    for (int Mt=0;Mt<4;Mt++){
      int tp=Mt>>1, smh=Mt&1;
      unsigned d[6];
      #pragma unroll
      for (int k=0;k<6;k++){
        int s0=2*k, s1=2*k+1;
        int r0=s0/3, g0=s0%3, r1=s1/3, g1=s1%3;
        unsigned lo=f2b(acc[Mt][g0][r0]+bv[g0]);
        unsigned hi=f2b(acc[Mt][g1][r1]+bv[g1]);
        d[k]=lo|(hi<<16);
      }
      long block16 = (long)blk32*2 + smh;
      u16* dst = out + (block16*T + t0+tp)*TP + jj*6144 + (w*64+lane)*12;
      u32x2 s0v; s0v.x=d[0]; s0v.y=d[1];
      u32x2 s1v; s1v.x=d[2]; s1v.y=d[3];
      u32x2 s2v; s2v.x=d[4]; s2v.y=d[5];
      __builtin_nontemporal_store(s0v, (u32x2*)dst);
      __builtin_nontemporal_store(s1v, (u32x2*)(dst+4));
      __builtin_nontemporal_store(s2v, (u32x2*)(dst+8));
    }
  }
}

// ---------------------------------------------------------------------------
// Recurrent encoder scans: packed gi via 6 per-lane u32x2 loads (jj-grouped
// layout), prefetch-1, no gi LDS. 172 WGs x 16 seqs, 1 barrier/step.
// (Round-2 proven structure; VGPR cap 128 — do not restructure, rounds
// 3/5/6/7 all regressed.)
// ---------------------------------------------------------------------------
__global__ __launch_bounds__(512, 2) void k_enc_scan(
    const int* c_mask, const int* q_mask, const int* a1m, const int* a2m,
    const u16* cWhhP, const u16* qWhhP, const u16* aWhhP,
    const float* cBhh, const float* qBhh, const float* aBhh,
    const u16* gi_c, const u16* gi_q, const u16* gi_a1, const u16* gi_a2,
    u16* enc_hi, u16* enc_lo, float* enc_qf, float* enc_a1f, float* enc_a2f)
{
  __shared__ u16 hhi[16][264];
  __shared__ u16 hlo[16][264];
  __shared__ int idxs[16];
  int bid=blockIdx.x, tid=threadIdx.x;
  const int* msk; const u16* W; const float* bhh; const u16* gi; int T, seq0, mode;
  u16 *ohi=0, *olo=0; float* of=0;
  if (bid<160){ msk=c_mask; W=cWhhP; bhh=cBhh; gi=gi_c+(long)bid*SLEN*TP; T=SLEN; seq0=bid*16; mode=0; ohi=enc_hi; olo=enc_lo; }
  else if (bid<164){ int e=bid-160; msk=q_mask; W=qWhhP; bhh=qBhh; gi=gi_q+(long)e*QLEN*TP; T=QLEN; seq0=e*16; mode=1; of=enc_qf; }
  else if (bid<168){ int e=bid-164; msk=a1m; W=aWhhP; bhh=aBhh; gi=gi_a1+(long)e*ALEN*TP; T=ALEN; seq0=e*16; mode=1; of=enc_a1f; }
  else             { int e=bid-168; msk=a2m; W=aWhhP; bhh=aBhh; gi=gi_a2+(long)e*ALEN*TP; T=ALEN; seq0=e*16; mode=1; of=enc_a2f; }
  if (tid<16){
    int len=0; const int* mr=msk+(seq0+tid)*T;
    for (int t=0;t<T;t++) len += (mr[t]==0);
    int id=len-1; if(id<0)id=0; if(id>T-1)id=T-1; idxs[tid]=id;
  }
  for (int i=tid;i<16*264;i+=512){ ((u16*)hhi)[i]=0; ((u16*)hlo)[i]=0; }
  const int w=tid>>6, lane=tid&63, c=lane&15, quad=lane>>4;
  float biasv[6];
  #pragma unroll
  for (int nt=0;nt<6;nt++) biasv[nt]=bhh[w*96+nt*16+c];
  uint4 breg[48];
  #pragma unroll
  for (int nt=0;nt<6;nt++)
    #pragma unroll
    for (int Kt=0;Kt<8;Kt++)
      breg[nt*8+Kt] = *(const uint4*)(W + (w*96+nt*16+c)*256 + Kt*32 + quad*8);
  float hreg[8];
  #pragma unroll
  for (int i=0;i<8;i++) hreg[i]=0.f;
  const u16* gp = gi + (w*64+lane)*12;
  u32x2 pA0=*(const u32x2*)(gp),      pA1=*(const u32x2*)(gp+4),    pA2=*(const u32x2*)(gp+8);
  u32x2 pA3=*(const u32x2*)(gp+6144), pA4=*(const u32x2*)(gp+6148), pA5=*(const u32x2*)(gp+6152);
  __syncthreads();
  int idxr[4];
  #pragma unroll
  for (int r=0;r<4;r++) idxr[r]=idxs[quad*4+r];

  for (int t=0;t<T;t++){
    u32x2 pB0,pB1,pB2,pB3,pB4,pB5;
    bool pf=(t+1<T);
    if (pf){
      const u16* gn = gp + (long)(t+1)*TP;
      pB0=*(const u32x2*)(gn);      pB1=*(const u32x2*)(gn+4);    pB2=*(const u32x2*)(gn+8);
      pB3=*(const u32x2*)(gn+6144); pB4=*(const u32x2*)(gn+6148); pB5=*(const u32x2*)(gn+6152);
    }
    f32x4 acc[6];
    #pragma unroll
    for (int nt=0;nt<6;nt++) acc[nt]=(f32x4){0.f,0.f,0.f,0.f};
    #pragma unroll
    for (int Kt=0;Kt<8;Kt++){
      bf16x8 a=*(const bf16x8*)&hhi[c][Kt*32+quad*8];
      #pragma unroll
      for (int nt=0;nt<6;nt++) acc[nt]=mfma16(a,*(const bf16x8*)&breg[nt*8+Kt],acc[nt]);
    }
    #pragma unroll
    for (int Kt=0;Kt<8;Kt++){
      bf16x8 a=*(const bf16x8*)&hlo[c][Kt*32+quad*8];
      #pragma unroll
      for (int nt=0;nt<6;nt++) acc[nt]=mfma16(a,*(const bf16x8*)&breg[nt*8+Kt],acc[nt]);
    }
    unsigned pd[12];
    *(u32x2*)&pd[0]=pA0; *(u32x2*)&pd[2]=pA1; *(u32x2*)&pd[4]=pA2;
    *(u32x2*)&pd[6]=pA3; *(u32x2*)&pd[8]=pA4; *(u32x2*)&pd[10]=pA5;
    #pragma unroll
    for (int r=0;r<4;r++){
      int m=quad*4+r;
      #pragma unroll
      for (int jj=0;jj<2;jj++){
        int j=w*32+jj*16+c;
        int ib=r*3;   // slot within jj region; words at pd[jj*6 + ...]
        float ir = b2f((u16)((pd[jj*6+(ib>>1)]     >> ((ib&1)*16)) & 0xffffu));
        float iz = b2f((u16)((pd[jj*6+((ib+1)>>1)] >> (((ib+1)&1)*16)) & 0xffffu));
        float in_= b2f((u16)((pd[jj*6+((ib+2)>>1)] >> (((ib+2)&1)*16)) & 0xffffu));
        float hr=acc[jj*3+0][r]+biasv[jj*3+0];
        float hz=acc[jj*3+1][r]+biasv[jj*3+1];
        float hn=acc[jj*3+2][r]+biasv[jj*3+2];
        float rr=sigm(ir+hr), zz=sigm(iz+hz), nn=tanh_(in_+rr*hn);
        float ho=hreg[r*2+jj];
        float hnew=(1.f-zz)*nn+zz*ho;
        hreg[r*2+jj]=hnew;
        u16 hi_=f2b(hnew); u16 lo_=f2b(hnew-b2f(hi_));
        hhi[m][j]=hi_; hlo[m][j]=lo_;
        if (t==idxr[r]){
          long o=(long)(seq0+m)*256+j;
          if (mode==0){ ohi[o]=hi_; olo[o]=lo_; }
          else of[o]=hnew;
        }
      }
    }
    __syncthreads();
    pA0=pB0; pA1=pB1; pA2=pB2; pA3=pB3; pA4=pB4; pA5=pB5;
  }
}

// ---------------------------------------------------------------------------
// FUSED gi_attn + gate-precompute + mem-init (independent kernels overlapped
// in one 321-block dispatch; LDS union 82.7KB).
//   bid <160 : gi_attn for (bblk, sentence s)    [was k_gi]
//   160..319 : gatepre n-split (seqgrp, nh)      [was k_gatepre]
//   bid==320 : mem_f = enc_qf init
// ---------------------------------------------------------------------------
__global__ __launch_bounds__(512, 1) void k_gi_gatepre(
    const u16* enc_hi, const u16* enc_lo, const u16* tWihP, const float* tBih,
    float* gi_attn, const float* enc_qf, float* mem_f,
    const u16* W1, const float* b1, float* partial)
{
  __shared__ float smem[20672];   // 82688 B union
  int bid=blockIdx.x, tid=threadIdx.x;
  if (bid==320){ for (int i=tid;i<64*256;i+=512) mem_f[i]=enc_qf[i]; return; }
  const int w=tid>>6, lane=tid&63, c=lane&15, quad=lane>>4;
  if (bid<160){
    // ---------------- gi branch ----------------
    u16* ahi=(u16*)smem;          // [16][264]
    u16* alo=ahi+16*264;
    int bblk=bid/40, s=bid-bblk*40, b0=bblk*16;
    {
      int row=tid>>5, ch=tid&31;
      long seq=(long)(b0+row)*NSENT + s;
      *(uint4*)((char*)(ahi+row*264)+ch*16) = *((const uint4*)(enc_hi+seq*256)+ch);
      *(uint4*)((char*)(alo+row*264)+ch*16) = *((const uint4*)(enc_lo+seq*256)+ch);
    }
    f32x4 acc[6];
    #pragma unroll
    for (int nt=0;nt<6;nt++) acc[nt]=(f32x4){0.f,0.f,0.f,0.f};
    __syncthreads();
    #pragma unroll
    for (int Kt=0;Kt<8;Kt++){
      bf16x8 a=*(const bf16x8*)(ahi + c*264 + Kt*32+quad*8);
      #pragma unroll
      for (int nt=0;nt<6;nt++){
        bf16x8 bfr=*(const bf16x8*)(tWihP + (w*96+nt*16+c)*256 + Kt*32 + quad*8);
        acc[nt]=mfma16(a,bfr,acc[nt]);
      }
    }
    #pragma unroll
    for (int Kt=0;Kt<8;Kt++){
      bf16x8 a=*(const bf16x8*)(alo + c*264 + Kt*32+quad*8);
      #pragma unroll
      for (int nt=0;nt<6;nt++){
        bf16x8 bfr=*(const bf16x8*)(tWihP + (w*96+nt*16+c)*256 + Kt*32 + quad*8);
        acc[nt]=mfma16(a,bfr,acc[nt]);
      }
    }
    float biasv[6];
    #pragma unroll
    for (int nt=0;nt<6;nt++) biasv[nt]=tBih[w*96+nt*16+c];
    float* dst = gi_attn + ((long)(bblk*40+s))*TP + (w*64+lane)*SLOT;
    #pragma unroll
    for (int d=0;d<6;d++){
      float4 v;
      #pragma unroll
      for (int e=0;e<4;e++){
        int idx=4*d+e;
        int r=idx/6, rem=idx%6, jj=rem/3, g=rem%3;
        ((float*)&v)[e]=acc[jj*3+g][r]+biasv[jj*3+g];
      }
      *(float4*)(dst+4*d)=v;
    }
  } else {
    // ---------------- gatepre branch ----------------
    float* ctf = smem;                   // [32][257]
    float* qvf = smem + 32*257;          // [32][257]
    u16*   ab  = (u16*)(smem + 2*32*257);// [32][264]
    int e=bid-160, seqgrp=e>>1, nh=e&1, seq0=seqgrp*32;
    #pragma unroll
    for (int p=0;p<16;p++){
      int i=p*512+tid; int row=i>>8, j=i&255;
      int grow=seq0+row; int b=grow/NSENT;
      ctf[row*257+j]=b2f(enc_hi[(long)grow*256+j])+b2f(enc_lo[(long)grow*256+j]);
      qvf[row*257+j]=enc_qf[b*256+j];
    }
    const int n = nh*128 + w*16 + c;
    f32x4 acc[2];
    {
      float bv=b1[n];
      acc[0]=(f32x4){bv,bv,bv,bv}; acc[1]=acc[0];
    }
    const int chl[4]={0,2,3,5};
    for (int ci=0; ci<4; ci++){
      int ch=chl[ci];
      __syncthreads();
      #pragma unroll
      for (int p=0;p<16;p++){
        int i=p*512+tid; int row=i>>8, j=i&255;
        float ct=ctf[row*257+j], qv=qvf[row*257+j];
        float v;
        if      (ch==0) v=ct;
        else if (ch==2) v=qv;
        else if (ch==3) v=ct*qv;
        else            v=fabsf(ct-qv);
        ab[row*264+j]=f2b(v);
      }
      __syncthreads();
      #pragma unroll
      for (int Kt=0;Kt<8;Kt++){
        bf16x8 a0=*(const bf16x8*)(ab + c*264 + Kt*32+quad*8);
        bf16x8 a1=*(const bf16x8*)(ab + (16+c)*264 + Kt*32+quad*8);
        bf16x8 bfr=*(const bf16x8*)(W1 + (long)n*1792 + ch*256 + Kt*32 + quad*8);
        acc[0]=mfma16(a0,bfr,acc[0]);
        acc[1]=mfma16(a1,bfr,acc[1]);
      }
    }
    #pragma unroll
    for (int Mt=0;Mt<2;Mt++)
      #pragma unroll
      for (int r=0;r<4;r++)
        partial[(long)(seq0+Mt*16+quad*4+r)*256 + n] = acc[Mt][r];
  }
}

// ---------------------------------------------------------------------------
// Per-episode gate, n-split: 160 blocks = (80 seq-groups x 2 n-halves).
// Each block writes its 128-n half-sum of tanh(.)*W2 to g[nh*SCTX+seq]
// (plain store, no memset/atomic needed). b2 + sigmoid applied in k_scan.
// ---------------------------------------------------------------------------
__global__ __launch_bounds__(512, 1) void k_gate(
    const u16* enc_hi, const u16* enc_lo, const float* mem_f,
    const float* partial, const u16* W1, const float* W2, float* g)
{
  __shared__ float ctf[32][257];
  __shared__ float mvf[32][257];
  __shared__ u16 ab[32][264];
  __shared__ float pl[32][8];
  int bid=blockIdx.x, tid=threadIdx.x;
  int seqgrp=bid>>1, nh=bid&1, seq0=seqgrp*32;
  #pragma unroll
  for (int p=0;p<16;p++){
    int i=p*512+tid; int row=i>>8, j=i&255;
    int grow=seq0+row; int b=grow/NSENT;
    ctf[row][j]=b2f(enc_hi[(long)grow*256+j])+b2f(enc_lo[(long)grow*256+j]);
    mvf[row][j]=mem_f[b*256+j];
  }
  const int w=tid>>6, lane=tid&63, c=lane&15, quad=lane>>4;
  const int n = nh*128 + w*16 + c;
  f32x4 acc[2];
  float w2v=W2[n];
  #pragma unroll
  for (int Mt=0;Mt<2;Mt++)
    #pragma unroll
    for (int r=0;r<4;r++)
      acc[Mt][r]=partial[(long)(seq0+Mt*16+quad*4+r)*256 + n];
  const int chl[3]={1,4,6};
  for (int ci=0; ci<3; ci++){
    int ch=chl[ci];
    __syncthreads();
    #pragma unroll
    for (int p=0;p<16;p++){
      int i=p*512+tid; int row=i>>8, j=i&255;
      float ct=ctf[row][j], mv=mvf[row][j];
      float v;
      if      (ch==1) v=mv;
      else if (ch==4) v=ct*mv;
      else            v=fabsf(ct-mv);
      ab[row][j]=f2b(v);
    }
    __syncthreads();
    #pragma unroll
    for (int Kt=0;Kt<8;Kt++){
      bf16x8 a0=*(const bf16x8*)&ab[c][Kt*32+quad*8];
      bf16x8 a1=*(const bf16x8*)&ab[16+c][Kt*32+quad*8];
      bf16x8 bfr=*(const bf16x8*)(W1 + (long)n*1792 + ch*256 + Kt*32 + quad*8);
      acc[0]=mfma16(a0,bfr,acc[0]);
      acc[1]=mfma16(a1,bfr,acc[1]);
    }
  }
  float pm[8];
  #pragma unroll
  for (int i=0;i<8;i++){
    int Mt=i>>2, r=i&3;
    pm[i]=tanh_(acc[Mt][r])*w2v;
  }
  #pragma unroll
  for (int off=1;off<16;off<<=1)
    #pragma unroll
    for (int i=0;i<8;i++) pm[i]+=__shfl_xor(pm[i],off,64);
  if (c==0){
    #pragma unroll
    for (int i=0;i<8;i++){ int m=(i>>2)*16+quad*4+(i&3); pl[m][w]=pm[i]; }
  }
  __syncthreads();
  if (tid<32){
    float s=0.f;
    #pragma unroll
    for (int ww=0;ww<8;ww++) s+=pl[tid][ww];
    g[nh*SCTX + seq0+tid]=s;
  }
}

// ---------------------------------------------------------------------------
// Episodic scan: 4 WGs x 16 batch rows; attn_Whh' VGPR-resident; packed
// gi_attn prefetch; all-lane elementwise; pi mem-GRU tail (lane-local).
// gl staging sums the two gate halves and applies sigm(. + b2).
// ---------------------------------------------------------------------------
__global__ __launch_bounds__(512, 2) void k_scan(
    const u16* tWhhP, const float* tBhh,
    const float* gi_attn, const float* g, const float* gb2,
    float* mem_f, const u16* mWihP, const u16* mWhhP,
    const float* mBih, const float* mBhh)
{
  __shared__ u16 hb[16][264];
  __shared__ u16 mhi[16][264];
  __shared__ u16 mlo[16][264];
  __shared__ float memfl[16][256];
  __shared__ float gl[16][40];
  int bid=blockIdx.x, tid=threadIdx.x, b0=bid*16;
  const int w=tid>>6, lane=tid&63, c=lane&15, quad=lane>>4;
  for (int i=tid;i<16*264;i+=512){ ((u16*)hb)[i]=0; }
  for (int i=tid;i<4096;i+=512){
    int m=i>>8, j=i&255;
    float v=mem_f[(b0+m)*256+j]; memfl[m][j]=v;
    u16 hi_=f2b(v); mhi[m][j]=hi_; mlo[m][j]=f2b(v-b2f(hi_));
  }
  {
    float b2s = gb2[0];
    for (int i=tid;i<640;i+=512){
      int m=i/40, s=i-m*40; int idx=(b0+m)*40+s;
      gl[m][s]=sigm(g[idx]+g[SCTX+idx]+b2s);
    }
  }
  float biasv[6];
  #pragma unroll
  for (int nt=0;nt<6;nt++) biasv[nt]=tBhh[w*96+nt*16+c];
  uint4 breg[48];
  #pragma unroll
  for (int nt=0;nt<6;nt++)
    #pragma unroll
    for (int Kt=0;Kt<8;Kt++)
      breg[nt*8+Kt] = *(const uint4*)(tWhhP + (w*96+nt*16+c)*256 + Kt*32 + quad*8);
  float hreg[8];
  #pragma unroll
  for (int i=0;i<8;i++) hreg[i]=0.f;
  const float* gp = gi_attn + ((long)bid*NSENT)*TP + (w*64+lane)*SLOT;
  float4 pA[6];
  #pragma unroll
  for (int d=0;d<6;d++) pA[d]=*(const float4*)(gp+4*d);
  __syncthreads();

  for (int s=0;s<NSENT;s++){
    float4 pB[6];
    bool pf=(s+1<NSENT);
    if (pf){
      const float* gn = gp + (long)(s+1)*TP;
      #pragma unroll
      for (int d=0;d<6;d++) pB[d]=*(const float4*)(gn+4*d);
    }
    f32x4 acc[6];
    #pragma unroll
    for (int nt=0;nt<6;nt++) acc[nt]=(f32x4){0.f,0.f,0.f,0.f};
    #pragma unroll
    for (int Kt=0;Kt<8;Kt++){
      bf16x8 a=*(const bf16x8*)&hb[c][Kt*32+quad*8];
      #pragma unroll
      for (int nt=0;nt<6;nt++) acc[nt]=mfma16(a,*(const bf16x8*)&breg[nt*8+Kt],acc[nt]);
    }
    const float* pf32 = (const float*)&pA[0];
    #pragma unroll
    for (int r=0;r<4;r++){
      int m=quad*4+r;
      float gv = gl[m][s];
      #pragma unroll
      for (int jj=0;jj<2;jj++){
        int j=w*32+jj*16+c;
        int ib=(r*2+jj)*3;
        float ir=pf32[ib], iz=pf32[ib+1], in_=pf32[ib+2];
        float hr=acc[jj*3+0][r]+biasv[jj*3+0];
        float hz=acc[jj*3+1][r]+biasv[jj*3+1];
        float hn=acc[jj*3+2][r]+biasv[jj*3+2];
        float rr=sigm(ir+hr), zz=sigm(iz+hz), nn=tanh_(in_+rr*hn);
        float ho=hreg[r*2+jj];
        float hc=(1.f-zz)*nn+zz*ho;
        float hnew=gv*hc+(1.f-gv)*ho;
        hreg[r*2+jj]=hnew;
        hb[m][j]=f2b(hnew);
      }
    }
    __syncthreads();
    #pragma unroll
    for (int d=0;d<6;d++) pA[d]=pB[d];
  }
  // memory GRU, pi layout: ai = e@mWih'^T, ah = mem(hi+lo)@mWhh'^T
  f32x4 ai[6], ah[6];
  #pragma unroll
  for (int nt=0;nt<6;nt++){ ai[nt]=(f32x4){0.f,0.f,0.f,0.f}; ah[nt]=ai[nt]; }
  #pragma unroll
  for (int Kt=0;Kt<8;Kt++){
    bf16x8 a=*(const bf16x8*)&hb[c][Kt*32+quad*8];
    #pragma unroll
    for (int nt=0;nt<6;nt++){
      bf16x8 bfr=*(const bf16x8*)(mWihP + (w*96+nt*16+c)*256 + Kt*32 + quad*8);
      ai[nt]=mfma16(a,bfr,ai[nt]);
    }
  }
  #pragma unroll
  for (int Kt=0;Kt<8;Kt++){
    bf16x8 a=*(const bf16x8*)&mhi[c][Kt*32+quad*8];
    #pragma unroll
    for (int nt=0;nt<6;nt++){
      bf16x8 bfr=*(const bf16x8*)(mWhhP + (w*96+nt*16+c)*256 + Kt*32 + quad*8);
      ah[nt]=mfma16(a,bfr,ah[nt]);
    }
  }
  #pragma unroll
  for (int Kt=0;Kt<8;Kt++){
    bf16x8 a=*(const bf16x8*)&mlo[c][Kt*32+quad*8];
    #pragma unroll
    for (int nt=0;nt<6;nt++){
      bf16x8 bfr=*(const bf16x8*)(mWhhP + (w*96+nt*16+c)*256 + Kt*32 + quad*8);
      ah[nt]=mfma16(a,bfr,ah[nt]);
    }
  }
  float bih6[6], bhh6[6];
  #pragma unroll
  for (int nt=0;nt<6;nt++){ bih6[nt]=mBih[w*96+nt*16+c]; bhh6[nt]=mBhh[w*96+nt*16+c]; }
  #pragma unroll
  for (int r=0;r<4;r++){
    int m=quad*4+r;
    #pragma unroll
    for (int jj=0;jj<2;jj++){
      int j=w*32+jj*16+c;
      float ir=ai[jj*3+0][r]+bih6[jj*3+0];
      float iz=ai[jj*3+1][r]+bih6[jj*3+1];
      float in_=ai[jj*3+2][r]+bih6[jj*3+2];
      float hr=ah[jj*3+0][r]+bhh6[jj*3+0];
      float hz=ah[jj*3+1][r]+bhh6[jj*3+1];
      float hn=ah[jj*3+2][r]+bhh6[jj*3+2];
      float rr=sigm(ir+hr), zz=sigm(iz+hz), nn=tanh_(in_+rr*hn);
      float mo=memfl[m][j];
      mem_f[(b0+m)*256+j]=(1.f-zz)*nn+zz*mo;
    }
  }
}

// ---------------------------------------------------------------------------
// Final head, all fp32.
// ---------------------------------------------------------------------------
__global__ void k_final(const float* mem_f, const float* a1f, const float* a2f,
    const float* W1o, const float* b1o, const float* W2o, const float* b2o, float* outp)
{
  __shared__ float af[768];
  __shared__ float tl[256];
  __shared__ float lg[2];
  int b=blockIdx.x, tid=threadIdx.x;
  af[tid]     = mem_f[b*256+tid];
  af[256+tid] = a1f[b*256+tid];
  af[512+tid] = a2f[b*256+tid];
  __syncthreads();
  float s=b1o[tid];
  const float* wr=W1o + (long)tid*768;
  for (int k=0;k<768;k++) s += af[k]*wr[k];
  tl[tid]=tanh_(s);
  __syncthreads();
  if (tid<2){
    float l=b2o[tid];
    const float* w2=W2o + tid*256;
    for (int k=0;k<256;k++) l += tl[k]*w2[k];
    lg[tid]=l;
  }
  __syncthreads();
  if (tid==0){
    float m=fmaxf(lg[0],lg[1]);
    float e0=__expf(lg[0]-m), e1=__expf(lg[1]-m);
    float inv=1.f/(e0+e1);
    outp[b*2]=e0*inv; outp[b*2+1]=e1*inv;
  }
}

// ---------------------------------------------------------------------------
extern "C" void kernel_launch(void* const* d_in, const int* in_sizes, int n_in,
                              void* d_out, int out_size, void* d_ws, size_t ws_size,
                              hipStream_t stream) {
  const int* c_p   = (const int*)d_in[0];
  const int* c_m   = (const int*)d_in[1];
  const int* q_p   = (const int*)d_in[2];
  const int* q_m   = (const int*)d_in[3];
  const int* a1p   = (const int*)d_in[4];
  const int* a1m   = (const int*)d_in[5];
  const int* a2p   = (const int*)d_in[6];
  const int* a2m   = (const int*)d_in[7];
  const float* embed = (const float*)d_in[8];
  const float* cWih=(const float*)d_in[9],  *cWhh=(const float*)d_in[10], *cbih=(const float*)d_in[11], *cbhh=(const float*)d_in[12];
  const float* qWih=(const float*)d_in[13], *qWhh=(const float*)d_in[14], *qbih=(const float*)d_in[15], *qbhh=(const float*)d_in[16];
  const float* aWih=(const float*)d_in[17], *aWhh=(const float*)d_in[18], *abih=(const float*)d_in[19], *abhh=(const float*)d_in[20];
  const float* tWih=(const float*)d_in[21], *tWhh=(const float*)d_in[22], *tbih=(const float*)d_in[23], *tbhh=(const float*)d_in[24];
  const float* mWih=(const float*)d_in[25], *mWhh=(const float*)d_in[26], *mbih=(const float*)d_in[27], *mbhh=(const float*)d_in[28];
  const float* gW1=(const float*)d_in[29], *gb1=(const float*)d_in[30], *gW2=(const float*)d_in[31], *gb2=(const float*)d_in[32];
  const float* oW1=(const float*)d_in[33], *ob1=(const float*)d_in[34], *oW2=(const float*)d_in[35], *ob2=(const float*)d_in[36];

  char* ws = (char*)d_ws;
  size_t off = 0;
  u16* P[10];
  for (int i=0;i<10;i++){ P[i]=(u16*)(ws+off); off+=393216; }
  u16* PgW1 =(u16*)(ws+off); off+=917504;
  float* B[10];
  for (int i=0;i<10;i++){ B[i]=(float*)(ws+off); off+=3072; }
  u16* gi_c =(u16*)(ws+off); off+=(size_t)160*SLEN*TP*2;   // 118 MB
  u16* gi_q =(u16*)(ws+off); off+=(size_t)4*QLEN*TP*2;
  u16* gi_a1=(u16*)(ws+off); off+=(size_t)4*ALEN*TP*2;
  u16* gi_a2=(u16*)(ws+off); off+=(size_t)4*ALEN*TP*2;
  u16* enc_hi=(u16*)(ws+off); off+=(size_t)SCTX*256*2;
  u16* enc_lo=(u16*)(ws+off); off+=(size_t)SCTX*256*2;
  float* enc_qf =(float*)(ws+off); off+=64*256*4;
  float* enc_a1f=(float*)(ws+off); off+=64*256*4;
  float* enc_a2f=(float*)(ws+off); off+=64*256*4;
  float* mem_f  =(float*)(ws+off); off+=64*256*4;
  float* gi_attn=(float*)(ws+off); off+=(size_t)160*TP*4;  // 7.9 MB
  float* partial=(float*)(ws+off); off+=(size_t)SCTX*256*4;
  float* gbuf   =(float*)(ws+off); off+=2*SCTX*4;

  k_prep<<<4751, 512, 0, stream>>>(cWih,cWhh,qWih,qWhh,aWih,aWhh,tWih,tWhh,mWih,mWhh,gW1,
      cbih,cbhh,qbih,qbhh,abih,abhh,tbih,tbhh,mbih,mbhh,
      P[0],P[1],P[2],P[3],P[4],P[5],P[6],P[7],P[8],P[9], PgW1,
      B[0],B[1],B[2],B[3],B[4],B[5],B[6],B[7],B[8],B[9]);

  k_xproj<<<1244, 512, 0, stream>>>(c_p,q_p,a1p,a2p, embed,
      P[0],P[2],P[4], B[0],B[2],B[4], gi_c,gi_q,gi_a1,gi_a2);

  k_enc_scan<<<172, 512, 0, stream>>>(c_m,q_m,a1m,a2m,
      P[1],P[3],P[5], B[1],B[3],B[5], gi_c,gi_q,gi_a1,gi_a2,
      enc_hi,enc_lo, enc_qf,enc_a1f,enc_a2f);

  k_gi_gatepre<<<321, 512, 0, stream>>>(enc_hi,enc_lo, P[6], B[6], gi_attn, enc_qf, mem_f,
      PgW1, gb1, partial);

  for (int ep=0; ep<3; ep++){
    k_gate<<<160, 512, 0, stream>>>(enc_hi,enc_lo, mem_f, partial, PgW1, gW2, gbuf);
    k_scan<<<4, 512, 0, stream>>>(P[7], B[7], gi_attn, gbuf, gb2, mem_f, P[8], P[9], B[8], B[9]);
  }

  k_final<<<64, 256, 0, stream>>>(mem_f, enc_a1f, enc_a2f, oW1, ob1, oW2, ob2, (float*)d_out);
}